// Round 5
// baseline (341.103 us; speedup 1.0000x reference)
//
#include <hip/hip_runtime.h>
#include <hip/hip_bf16.h>
#include <math.h>

#define L 4096
#define C 128
#define DI 256
#define NST 16
#define NS 3
#define NCH 256
#define CT 16
#define R3 12288   // (s,d,n) = 3*256*16

__device__ __forceinline__ float siluf(float x){ return x / (1.f + __expf(-x)); }
__device__ __forceinline__ float geluf(float x){ return 0.5f*x*(1.f + erff(x*0.70710678118654752f)); }

__device__ __forceinline__ int permf(int s, int l){
  if(s==0) return l;
  if(s==1) return ((l&15)<<8) | ((l>>8)<<4) | ((l>>4)&15);
  return (((l>>4)&15)<<8) | ((l&15)<<4) | (l>>8);
}

// K0: fold out_proj & proj -> M[(s*256+d)*128+o]
__global__ void k_M(const float* __restrict__ opw, const float* __restrict__ pw,
                    float* __restrict__ Mw){
  int b = blockIdx.x;              // s*128+o
  int o = b & 127, s = b >> 7;
  int d = threadIdx.x;
  float acc = 0.f;
  for(int c=0;c<C;c++) acc += opw[c*DI + d] * pw[o*384 + s*128 + c];
  Mw[(s*256+d)*128 + o] = acc;
}

// K2: fused LN(channel,1e-6)+LN(row,1e-5), then Z = Y0 @ ipw^T. A staged k-major.
__global__ void k_lngemm(const float* __restrict__ x, const float* __restrict__ lw,
                         const float* __restrict__ lb, const float* __restrict__ mw,
                         const float* __restrict__ mb, const float* __restrict__ ipw,
                         float* __restrict__ Z){
  __shared__ float As[128][68];    // [c][p]
  __shared__ float Bs[64][132];    // [j][c]
  int p0 = blockIdx.x*64, j0 = blockIdx.y*64;
  int tid = threadIdx.x;
  // A: x is channel-major -> natural k-major float4 writes. 128*64 = 8192 floats.
  for(int q=0;q<8;q++){
    int f = q*1024 + tid*4; int cc = f>>6, p = f&63;
    float4 v = *(const float4*)&x[cc*L + p0 + p];
    *(float4*)&As[cc][p] = v;
  }
  // B: 64*128 = 8192 floats
  for(int q=0;q<8;q++){
    int f = q*1024 + tid*4; int j = f>>7, k = f&127;
    float4 b = *(const float4*)&ipw[(j0+j)*C + k];
    *(float4*)&Bs[j][k] = b;
  }
  __syncthreads();
  // LN per p-column over 128 channels; 4 threads per column, stagger kg*2
  {
    int p = tid>>2, kg = tid&3;
    float s=0.f, sq=0.f;
    #pragma unroll
    for(int i=0;i<32;i++){
      int k = kg*32 + ((i + kg*2)&31);
      float v = As[k][p]; s += v; sq += v*v;
    }
    s  += __shfl_xor(s,1);  s  += __shfl_xor(s,2);
    sq += __shfl_xor(sq,1); sq += __shfl_xor(sq,2);
    float m1 = s*(1.f/C);
    float r1 = rsqrtf(sq*(1.f/C) - m1*m1 + 1e-6f);
    float s2=0.f, sq2=0.f;
    #pragma unroll
    for(int i=0;i<32;i++){
      int k = kg*32 + ((i + kg*2)&31);
      float t = lw[k]*((As[k][p]-m1)*r1) + lb[k];
      s2 += t; sq2 += t*t;
    }
    s2  += __shfl_xor(s2,1);  s2  += __shfl_xor(s2,2);
    sq2 += __shfl_xor(sq2,1); sq2 += __shfl_xor(sq2,2);
    float m2 = s2*(1.f/C);
    float r2 = rsqrtf(sq2*(1.f/C) - m2*m2 + 1e-5f);
    #pragma unroll
    for(int i=0;i<32;i++){
      int k = kg*32 + ((i + kg*2)&31);
      float t = lw[k]*((As[k][p]-m1)*r1) + lb[k];
      As[k][p] = mw[k]*((t-m2)*r2) + mb[k];
    }
  }
  __syncthreads();
  int og = tid & 15, r4 = tid >> 4;
  float acc[4][4] = {};
  for(int k=0;k<128;k++){
    float4 av = *(const float4*)&As[k][r4*4];
    float a[4] = {av.x, av.y, av.z, av.w};
    float b[4];
    #pragma unroll
    for(int j=0;j<4;j++) b[j] = Bs[og+16*j][k];
    #pragma unroll
    for(int i=0;i<4;i++)
      #pragma unroll
      for(int j=0;j<4;j++) acc[i][j] += a[i]*b[j];
  }
  #pragma unroll
  for(int i=0;i<4;i++)
    #pragma unroll
    for(int j=0;j<4;j++)
      Z[(p0+r4*4+i)*512 + j0 + og + 16*j] = acc[i][j];
}

// K3: causal depthwise conv (k=4) + bias + silu
__global__ void k_conv(const float* __restrict__ Z, const float* __restrict__ cw,
                       const float* __restrict__ cb, float* __restrict__ xc){
  int bl = blockIdx.x;            // s*4096 + l
  int s = bl >> 12, l = bl & 4095;
  int d = threadIdx.x;
  float acc = cb[d];
  #pragma unroll
  for(int k=0;k<4;k++){
    int lk = l - 3 + k;
    if(lk >= 0){
      int p = permf(s, lk);
      acc += cw[d*4+k] * Z[p*512 + d];
    }
  }
  xc[bl*DI + d] = siluf(acc);
}

// K4: fused x_dbl + delta. Block: 16 rows; each wave 4 rows (shuffle-reduce),
// dt kept in LDS, then delta = softplus(dt@dtw^T+b) coalesced over d.
__global__ void k_xd(const float* __restrict__ xc, const float* __restrict__ xpw,
                     const float* __restrict__ dtw, const float* __restrict__ dtb,
                     float* __restrict__ Bc, float* __restrict__ Cc,
                     float* __restrict__ delta){
  __shared__ float dts[16][8];
  int r0 = blockIdx.x*16;
  int tid = threadIdx.x;
  int w = tid>>6, lane = tid&63;
  for(int rr=0; rr<4; rr++){
    int lr = w*4 + rr;
    int row = r0 + lr;
    float4 xv = *(const float4*)&xc[row*DI + lane*4];
    float res = 0.f;
    #pragma unroll
    for(int col=0; col<40; col++){
      float4 wv = *(const float4*)&xpw[col*DI + lane*4];
      float p = xv.x*wv.x + xv.y*wv.y + xv.z*wv.z + xv.w*wv.w;
      p += __shfl_xor(p,1); p += __shfl_xor(p,2); p += __shfl_xor(p,4);
      p += __shfl_xor(p,8); p += __shfl_xor(p,16); p += __shfl_xor(p,32);
      if(lane == col) res = p;
    }
    if(lane < 8)       dts[lr][lane] = res;
    else if(lane < 24) Bc[row*NST + lane - 8]  = res;
    else if(lane < 40) Cc[row*NST + lane - 24] = res;
  }
  __syncthreads();
  int d = tid;
  float4 w0 = *(const float4*)&dtw[d*8];
  float4 w1 = *(const float4*)&dtw[d*8+4];
  float bb = dtb[d];
  #pragma unroll 4
  for(int r=0;r<16;r++){
    float acc = bb + dts[r][0]*w0.x + dts[r][1]*w0.y + dts[r][2]*w0.z + dts[r][3]*w0.w
                   + dts[r][4]*w1.x + dts[r][5]*w1.y + dts[r][6]*w1.z + dts[r][7]*w1.w;
    delta[(r0+r)*DI + d] = (acc > 20.f) ? acc : log1pf(__expf(acc));
  }
}

// K5: scan pass A — chunk aggregates (P,S), CT=16, 4 states/thread
__global__ void k_scanA(const float* __restrict__ delta, const float* __restrict__ xc,
                        const float* __restrict__ Bc, const float* __restrict__ A_log,
                        float* __restrict__ aggA, float* __restrict__ aggB){
  int b = blockIdx.x;                       // 3072 = 3*256*4
  int ng = b & 3, ch = (b>>2)&255, s = b>>10;
  int d = threadIdx.x;
  int n0 = ng*4;
  float Aa[4], P[4] = {1.f,1.f,1.f,1.f}, S[4] = {0.f,0.f,0.f,0.f};
  #pragma unroll
  for(int j=0;j<4;j++) Aa[j] = -__expf(A_log[d*NST + n0 + j]);
  int base = s*L + ch*CT;
  #pragma unroll
  for(int st=0; st<CT; st++){
    int row = base + st;
    float dl = delta[row*DI + d];
    float u  = xc[row*DI + d];
    float4 bv = *(const float4*)&Bc[row*NST + n0];
    float dlu = dl*u;
    float a;
    a = __expf(dl*Aa[0]); S[0] = a*S[0] + dlu*bv.x; P[0] *= a;
    a = __expf(dl*Aa[1]); S[1] = a*S[1] + dlu*bv.y; P[1] *= a;
    a = __expf(dl*Aa[2]); S[2] = a*S[2] + dlu*bv.z; P[2] *= a;
    a = __expf(dl*Aa[3]); S[3] = a*S[3] + dlu*bv.w; P[3] *= a;
  }
  int idx0 = ch*R3 + s*256 + d;
  #pragma unroll
  for(int j=0;j<4;j++){
    int idx = idx0 + (n0+j)*768;
    aggA[idx] = P[j]; aggB[idx] = S[j];
  }
}

// K6: prefix over 256 chunk aggregates
__global__ void k_scanB(const float* __restrict__ aggA, const float* __restrict__ aggB,
                        float* __restrict__ hIn){
  int j = blockIdx.x*256 + threadIdx.x;  // < 12288
  float h = 0.f;
  #pragma unroll 4
  for(int c=0;c<NCH;c++){
    hIn[c*R3 + j] = h;
    h = aggA[c*R3 + j]*h + aggB[c*R3 + j];
  }
}

// K7: scan pass C — 16 states/thread, CT=16, gate + store yz
__global__ void k_scanC(const float* __restrict__ delta, const float* __restrict__ xc,
                        const float* __restrict__ Bc, const float* __restrict__ Cc,
                        const float* __restrict__ A_log, const float* __restrict__ Dp,
                        const float* __restrict__ Z, const float* __restrict__ hIn,
                        float* __restrict__ yz){
  int b = blockIdx.x;                 // 768 = 3*256
  int ch = b & 255, s = b >> 8;
  int d = threadIdx.x;
  float Aa[16], h[16];
  #pragma unroll
  for(int n=0;n<16;n++) Aa[n] = -__expf(A_log[d*NST + n]);
  #pragma unroll
  for(int n=0;n<16;n++) h[n] = hIn[ch*R3 + n*768 + s*256 + d];
  float Dv = Dp[d];
  int base = s*L + ch*CT;
  #pragma unroll 2
  for(int st=0; st<CT; st++){
    int row = base + st;
    float dl = delta[row*DI + d];
    float u  = xc[row*DI + d];
    float dlu = dl*u;
    const float4* Bp = (const float4*)&Bc[row*NST];
    const float4* Cp = (const float4*)&Cc[row*NST];
    float y = u*Dv;
    #pragma unroll
    for(int q=0;q<4;q++){
      float4 bv = Bp[q], cv = Cp[q];
      float a;
      a = __expf(dl*Aa[4*q+0]); h[4*q+0] = a*h[4*q+0] + dlu*bv.x; y += h[4*q+0]*cv.x;
      a = __expf(dl*Aa[4*q+1]); h[4*q+1] = a*h[4*q+1] + dlu*bv.y; y += h[4*q+1]*cv.y;
      a = __expf(dl*Aa[4*q+2]); h[4*q+2] = a*h[4*q+2] + dlu*bv.z; y += h[4*q+2]*cv.z;
      a = __expf(dl*Aa[4*q+3]); h[4*q+3] = a*h[4*q+3] + dlu*bv.w; y += h[4*q+3]*cv.w;
    }
    int l = ch*CT + st;
    int p = permf(s, l);
    float zv = Z[p*512 + 256 + d];
    yz[(s*L + l)*DI + d] = y * siluf(zv);
  }
}

// K8: out1 partials (tile 64x128, split-K=6, two 64-k phases, 51KB LDS)
__global__ void k_proj(const float* __restrict__ yz, const float* __restrict__ Mw,
                       float* __restrict__ pp){
  __shared__ float As[64][68];     // [r][k]
  __shared__ float Bs[64][132];    // [k][o]
  int p0 = blockIdx.x*64; int kc = blockIdx.y;  // 0..5
  int s = kc >> 1, d0 = (kc & 1)*128;
  int tid = threadIdx.x;
  int og = tid & 15, r4 = tid >> 4;
  float acc[4][8] = {};
  for(int kk=0; kk<2; kk++){
    int kb = d0 + kk*64;
    for(int q=0;q<4;q++){
      int f = q*1024 + tid*4; int r = f>>6, k = f&63;
      float4 a = *(const float4*)&yz[(s*L + p0 + r)*DI + kb + k];
      *(float4*)&As[r][k] = a;
    }
    for(int q=0;q<8;q++){
      int f = q*1024 + tid*4; int k = f>>7, o = f&127;
      float4 b = *(const float4*)&Mw[(s*256 + kb + k)*128 + o];
      *(float4*)&Bs[k][o] = b;
    }
    __syncthreads();
    for(int k=0;k<64;k++){
      float a[4];
      #pragma unroll
      for(int i=0;i<4;i++) a[i] = As[r4*4+i][k];
      #pragma unroll
      for(int j=0;j<8;j++){
        float bb = Bs[k][og+16*j];
        #pragma unroll
        for(int i=0;i<4;i++) acc[i][j] += a[i]*bb;
      }
    }
    __syncthreads();
  }
  float* dst = pp + kc*524288;
  #pragma unroll
  for(int i=0;i<4;i++)
    #pragma unroll
    for(int j=0;j<8;j++)
      dst[(p0+r4*4+i)*C + og + 16*j] = acc[i][j];
}

// K8b: ores = sum(pp) + x^T + pb
__global__ void k_pred(const float* __restrict__ pp, const float* __restrict__ x,
                       const float* __restrict__ pb, float* __restrict__ ores){
  __shared__ float Xs[16][129];
  int p0 = blockIdx.x*16; int tid = threadIdx.x;
  for(int q=0;q<8;q++){
    int f = q*256 + tid; int pl = f&15, o = f>>4;
    Xs[pl][o] = x[o*L + p0 + pl];
  }
  __syncthreads();
  for(int q=0;q<8;q++){
    int f = q*256 + tid; int o = f&127, pl = f>>7;
    int idx = (p0+pl)*C + o;
    float v = pp[idx] + pp[524288+idx] + pp[1048576+idx]
            + pp[1572864+idx] + pp[2097152+idx] + pp[2621440+idx];
    ores[idx] = v + Xs[pl][o] + pb[o];
  }
}

// K9b: fused LN(1e-6) + fc1 + gelu
__global__ void k_fc1(const float* __restrict__ ores, const float* __restrict__ lw,
                      const float* __restrict__ lb, const float* __restrict__ w1,
                      const float* __restrict__ b1, float* __restrict__ H){
  __shared__ float As[64][129];
  __shared__ float Bs[64][129];
  int p0 = blockIdx.x*64, j0 = blockIdx.y*64;
  int tid = threadIdx.x;
  for(int q=0;q<8;q++){
    int f = q*1024 + tid*4; int r = f>>7, k = f&127;
    float4 a = *(const float4*)&ores[(p0+r)*C + k];
    As[r][k]=a.x; As[r][k+1]=a.y; As[r][k+2]=a.z; As[r][k+3]=a.w;
    float4 b = *(const float4*)&w1[(j0+r)*C + k];
    Bs[r][k]=b.x; Bs[r][k+1]=b.y; Bs[r][k+2]=b.z; Bs[r][k+3]=b.w;
  }
  __syncthreads();
  {
    int r = tid>>2, kg = tid&3;
    float s=0.f, sq=0.f;
    #pragma unroll
    for(int i=0;i<32;i++){
      int k = kg*32 + ((i + kg*8)&31);
      float v = As[r][k]; s += v; sq += v*v;
    }
    s  += __shfl_xor(s,1);  s  += __shfl_xor(s,2);
    sq += __shfl_xor(sq,1); sq += __shfl_xor(sq,2);
    float m1 = s*(1.f/C);
    float r1 = rsqrtf(sq*(1.f/C) - m1*m1 + 1e-6f);
    #pragma unroll
    for(int i=0;i<32;i++){
      int k = kg*32 + ((i + kg*8)&31);
      As[r][k] = lw[k]*((As[r][k]-m1)*r1) + lb[k];
    }
  }
  __syncthreads();
  int og = tid & 15, r4 = tid >> 4;
  float acc[4][4] = {};
  for(int k=0;k<128;k++){
    float a[4], b[4];
    #pragma unroll
    for(int i=0;i<4;i++) a[i] = As[r4*4+i][k];
    #pragma unroll
    for(int j=0;j<4;j++) b[j] = Bs[og+16*j][k];
    #pragma unroll
    for(int i=0;i<4;i++)
      #pragma unroll
      for(int j=0;j<4;j++) acc[i][j] += a[i]*b[j];
  }
  #pragma unroll
  for(int i=0;i<4;i++)
    #pragma unroll
    for(int j=0;j<4;j++){
      int jj = j0 + og + 16*j;
      H[(p0+r4*4+i)*512 + jj] = geluf(acc[i][j] + b1[jj]);
    }
}

// K9c: fc2 partials (tile 64x128, split-K=4, two 64-k phases, 52KB LDS)
__global__ void k_fc2(const float* __restrict__ H, const float* __restrict__ w2,
                      float* __restrict__ fp){
  __shared__ float As[64][68];     // [r][k]
  __shared__ float Bs[128][68];    // [o][k]
  int p0 = blockIdx.x*64; int kc = blockIdx.y;
  int tid = threadIdx.x;
  int og = tid & 15, r4 = tid >> 4;
  float acc[4][8] = {};
  for(int kk=0; kk<2; kk++){
    int kb = kc*128 + kk*64;
    for(int q=0;q<4;q++){
      int f = q*1024 + tid*4; int r = f>>6, k = f&63;
      float4 a = *(const float4*)&H[(p0+r)*512 + kb + k];
      *(float4*)&As[r][k] = a;
    }
    for(int q=0;q<8;q++){
      int f = q*1024 + tid*4; int o = f>>6, k = f&63;
      float4 b = *(const float4*)&w2[o*512 + kb + k];
      *(float4*)&Bs[o][k] = b;
    }
    __syncthreads();
    for(int k=0;k<64;k++){
      float a[4];
      #pragma unroll
      for(int i=0;i<4;i++) a[i] = As[r4*4+i][k];
      #pragma unroll
      for(int j=0;j<8;j++){
        float bb = Bs[og+16*j][k];
        #pragma unroll
        for(int i=0;i<4;i++) acc[i][j] += a[i]*bb;
      }
    }
    __syncthreads();
  }
  float* dst = fp + kc*524288;
  #pragma unroll
  for(int i=0;i<4;i++)
    #pragma unroll
    for(int j=0;j<8;j++)
      dst[(p0+r4*4+i)*C + og + 16*j] = acc[i][j];
}

// K9d: out = sum(fp) + b2 + ores, transposed store
__global__ void k_fred(const float* __restrict__ fp, const float* __restrict__ b2,
                       const float* __restrict__ ores, float* __restrict__ out){
  __shared__ float S[128][17];
  int p0 = blockIdx.x*16; int tid = threadIdx.x;
  for(int q=0;q<8;q++){
    int f = q*256 + tid; int o = f&127, pl = f>>7;
    int idx = (p0+pl)*C + o;
    float v = fp[idx] + fp[524288+idx] + fp[1048576+idx] + fp[1572864+idx];
    S[o][pl] = v + b2[o] + ores[idx];
  }
  __syncthreads();
  for(int q=0;q<8;q++){
    int f = q*256 + tid; int pl = f&15, o = f>>4;
    out[o*L + p0 + pl] = S[o][pl];
  }
}

extern "C" void kernel_launch(void* const* d_in, const int* in_sizes, int n_in,
                              void* d_out, int out_size, void* d_ws, size_t ws_size,
                              hipStream_t stream) {
  const float* x     = (const float*)d_in[0];
  const float* ln_w  = (const float*)d_in[1];
  const float* ln_b  = (const float*)d_in[2];
  const float* mw    = (const float*)d_in[3];
  const float* mb    = (const float*)d_in[4];
  const float* ipw   = (const float*)d_in[5];
  const float* cw    = (const float*)d_in[6];
  const float* cb    = (const float*)d_in[7];
  const float* xpw   = (const float*)d_in[8];
  const float* dtw   = (const float*)d_in[9];
  const float* dtb   = (const float*)d_in[10];
  const float* A_log = (const float*)d_in[11];
  const float* Dp    = (const float*)d_in[12];
  const float* opw   = (const float*)d_in[13];
  const float* pw    = (const float*)d_in[14];
  const float* pb    = (const float*)d_in[15];
  const float* w1    = (const float*)d_in[16];
  const float* b1    = (const float*)d_in[17];
  const float* w2    = (const float*)d_in[18];
  const float* b2    = (const float*)d_in[19];
  float* out = (float*)d_out;

  float* ws = (float*)d_ws;
  float* Z     = ws;                       // 2097152
  float* xc    = Z     + 2097152;          // 3145728
  float* delta = xc    + 3145728;          // 3145728
  float* dt    = delta + 3145728;          // 98304 (spacer)
  float* Bc    = dt    + 98304;            // 196608
  float* Cc    = Bc    + 196608;           // 196608
  float* aggA  = Cc    + 196608;           // 3145728 (256 chunks * 12288)
  float* aggB  = aggA  + 3145728;          // 3145728
  float* hIn   = aggB  + 3145728;          // 3145728
  float* Mw    = hIn   + 3145728;          // 98304
  float* ores  = Mw    + 98304;            // 524288
  // aliases (dead-after-scanC regions reused)
  float* yz = aggA;    // 3145728, after scanB consumed aggA/aggB
  float* pp = delta;   // 6*524288 = 3145728, after scanC
  float* H  = Z;       // 2097152, after scanC
  float* fp = xc;      // 4*524288 = 2097152, after scanC

  k_M     <<<384, 256, 0, stream>>>(opw, pw, Mw);
  k_lngemm<<<dim3(64,8), 256, 0, stream>>>(x, ln_w, ln_b, mw, mb, ipw, Z);
  k_conv  <<<NS*L, 256, 0, stream>>>(Z, cw, cb, xc);
  k_xd    <<<768, 256, 0, stream>>>(xc, xpw, dtw, dtb, Bc, Cc, delta);
  k_scanA <<<3072, 256, 0, stream>>>(delta, xc, Bc, A_log, aggA, aggB);
  k_scanB <<<48, 256, 0, stream>>>(aggA, aggB, hIn);
  k_scanC <<<768, 256, 0, stream>>>(delta, xc, Bc, Cc, A_log, Dp, Z, hIn, yz);
  k_proj  <<<dim3(64,6), 256, 0, stream>>>(yz, Mw, pp);
  k_pred  <<<256, 256, 0, stream>>>(pp, x, pb, ores);
  k_fc1   <<<dim3(64,8), 256, 0, stream>>>(ores, ln_w, ln_b, w1, b1, H);
  k_fc2   <<<dim3(64,4), 256, 0, stream>>>(H, w2, fp);
  k_fred  <<<256, 256, 0, stream>>>(fp, b2, ores, out);
}

// Round 6
// 304.734 us; speedup vs baseline: 1.1193x; 1.1193x over previous
//
#include <hip/hip_runtime.h>
#include <hip/hip_bf16.h>
#include <math.h>

#define L 4096
#define C 128
#define DI 256
#define NST 16
#define NS 3
#define NCH 256
#define CT 16
#define R3 12288   // (s,d,n) = 3*256*16

__device__ __forceinline__ float siluf(float x){ return x / (1.f + __expf(-x)); }
__device__ __forceinline__ float geluf(float x){ return 0.5f*x*(1.f + erff(x*0.70710678118654752f)); }

__device__ __forceinline__ int permf(int s, int l){
  if(s==0) return l;
  if(s==1) return ((l&15)<<8) | ((l>>8)<<4) | ((l>>4)&15);
  return (((l>>4)&15)<<8) | ((l&15)<<4) | (l>>8);
}

// K0: fold out_proj & proj -> M[(s*256+d)*128+o]
__global__ void k_M(const float* __restrict__ opw, const float* __restrict__ pw,
                    float* __restrict__ Mw){
  int b = blockIdx.x;              // s*128+o
  int o = b & 127, s = b >> 7;
  int d = threadIdx.x;
  float acc = 0.f;
  for(int c=0;c<C;c++) acc += opw[c*DI + d] * pw[o*384 + s*128 + c];
  Mw[(s*256+d)*128 + o] = acc;
}

// K2: fused LN(channel,1e-6)+LN(row,1e-5), then Z = Y0 @ ipw^T. A staged k-major.
__global__ void k_lngemm(const float* __restrict__ x, const float* __restrict__ lw,
                         const float* __restrict__ lb, const float* __restrict__ mw,
                         const float* __restrict__ mb, const float* __restrict__ ipw,
                         float* __restrict__ Z){
  __shared__ float As[128][68];    // [c][p]
  __shared__ float Bs[64][132];    // [j][c]
  int p0 = blockIdx.x*64, j0 = blockIdx.y*64;
  int tid = threadIdx.x;
  for(int q=0;q<8;q++){
    int f = q*1024 + tid*4; int cc = f>>6, p = f&63;
    float4 v = *(const float4*)&x[cc*L + p0 + p];
    *(float4*)&As[cc][p] = v;
  }
  for(int q=0;q<8;q++){
    int f = q*1024 + tid*4; int j = f>>7, k = f&127;
    float4 b = *(const float4*)&ipw[(j0+j)*C + k];
    *(float4*)&Bs[j][k] = b;
  }
  __syncthreads();
  {
    int p = tid>>2, kg = tid&3;
    float s=0.f, sq=0.f;
    #pragma unroll
    for(int i=0;i<32;i++){
      int k = kg*32 + ((i + kg*2)&31);
      float v = As[k][p]; s += v; sq += v*v;
    }
    s  += __shfl_xor(s,1);  s  += __shfl_xor(s,2);
    sq += __shfl_xor(sq,1); sq += __shfl_xor(sq,2);
    float m1 = s*(1.f/C);
    float r1 = rsqrtf(sq*(1.f/C) - m1*m1 + 1e-6f);
    float s2=0.f, sq2=0.f;
    #pragma unroll
    for(int i=0;i<32;i++){
      int k = kg*32 + ((i + kg*2)&31);
      float t = lw[k]*((As[k][p]-m1)*r1) + lb[k];
      s2 += t; sq2 += t*t;
    }
    s2  += __shfl_xor(s2,1);  s2  += __shfl_xor(s2,2);
    sq2 += __shfl_xor(sq2,1); sq2 += __shfl_xor(sq2,2);
    float m2 = s2*(1.f/C);
    float r2 = rsqrtf(sq2*(1.f/C) - m2*m2 + 1e-5f);
    #pragma unroll
    for(int i=0;i<32;i++){
      int k = kg*32 + ((i + kg*2)&31);
      float t = lw[k]*((As[k][p]-m1)*r1) + lb[k];
      As[k][p] = mw[k]*((t-m2)*r2) + mb[k];
    }
  }
  __syncthreads();
  int og = tid & 15, r4 = tid >> 4;
  float acc[4][4] = {};
  for(int k=0;k<128;k++){
    float4 av = *(const float4*)&As[k][r4*4];
    float a[4] = {av.x, av.y, av.z, av.w};
    float b[4];
    #pragma unroll
    for(int j=0;j<4;j++) b[j] = Bs[og+16*j][k];
    #pragma unroll
    for(int i=0;i<4;i++)
      #pragma unroll
      for(int j=0;j<4;j++) acc[i][j] += a[i]*b[j];
  }
  #pragma unroll
  for(int i=0;i<4;i++)
    #pragma unroll
    for(int j=0;j<4;j++)
      Z[(p0+r4*4+i)*512 + j0 + og + 16*j] = acc[i][j];
}

// K3: causal depthwise conv (k=4) + bias + silu
__global__ void k_conv(const float* __restrict__ Z, const float* __restrict__ cw,
                       const float* __restrict__ cb, float* __restrict__ xc){
  int bl = blockIdx.x;            // s*4096 + l
  int s = bl >> 12, l = bl & 4095;
  int d = threadIdx.x;
  float acc = cb[d];
  #pragma unroll
  for(int k=0;k<4;k++){
    int lk = l - 3 + k;
    if(lk >= 0){
      int p = permf(s, lk);
      acc += cw[d*4+k] * Z[p*512 + d];
    }
  }
  xc[bl*DI + d] = siluf(acc);
}

// K4: xdbl as tiled GEMM (M=12288,N=40,K=256) + fused delta + B/C writes.
// Block: 32 rows. LDS As[32][257] (33KB) conflict-free; BCs[40][33] transpose buf.
__global__ void k_xd2(const float* __restrict__ xc, const float* __restrict__ xpw,
                      const float* __restrict__ dtw, const float* __restrict__ dtb,
                      float* __restrict__ Bc, float* __restrict__ Cc,
                      float* __restrict__ delta){
  __shared__ float As[32][257];
  __shared__ float BCs[40][33];
  int r0 = blockIdx.x*32;
  int tid = threadIdx.x;
  // stage 32 rows of xc (32*256 floats)
  for(int q=0;q<8;q++){
    int f = q*1024 + tid*4; int c = f>>8, k = f&255;
    float4 v = *(const float4*)&xc[(r0+c)*DI + k];
    *(float4*)&As[c][k] = v;
  }
  __syncthreads();
  // GEMM: thread (grp=tid>>5, c=tid&31) computes cols grp*5..grp*5+4 for row c
  int grp = tid>>5, c = tid&31;
  const float* w0 = xpw + grp*5*DI;
  float acc[5] = {0.f,0.f,0.f,0.f,0.f};
  #pragma unroll 4
  for(int k4=0;k4<64;k4++){
    float4 a = *(const float4*)&As[c][k4*4];
    #pragma unroll
    for(int j=0;j<5;j++){
      float4 w = *(const float4*)&w0[j*DI + k4*4];
      acc[j] += a.x*w.x + a.y*w.y + a.z*w.z + a.w*w.w;
    }
  }
  #pragma unroll
  for(int j=0;j<5;j++) BCs[grp*5+j][c] = acc[j];
  __syncthreads();
  // delta: d = tid, all 32 rows; dt rows are BCs[0..7][r] (broadcast reads)
  {
    int d = tid;
    float4 ww0 = *(const float4*)&dtw[d*8];
    float4 ww1 = *(const float4*)&dtw[d*8+4];
    float bb = dtb[d];
    for(int r=0;r<32;r++){
      float aa = bb + BCs[0][r]*ww0.x + BCs[1][r]*ww0.y + BCs[2][r]*ww0.z + BCs[3][r]*ww0.w
                    + BCs[4][r]*ww1.x + BCs[5][r]*ww1.y + BCs[6][r]*ww1.z + BCs[7][r]*ww1.w;
      delta[(r0+r)*DI + d] = (aa > 20.f) ? aa : log1pf(__expf(aa));
    }
  }
  // B/C row-major coalesced writes: thread -> (c2=tid>>3, n2=(tid&7)*2)
  {
    int c2 = tid>>3, n2 = (tid&7)*2;
    float2 bv = make_float2(BCs[8+n2][c2],  BCs[9+n2][c2]);
    float2 cv = make_float2(BCs[24+n2][c2], BCs[25+n2][c2]);
    *(float2*)&Bc[(r0+c2)*NST + n2] = bv;
    *(float2*)&Cc[(r0+c2)*NST + n2] = cv;
  }
}

// K5: scan pass A — chunk aggregates (P,S), CT=16, 4 states/thread
__global__ void k_scanA(const float* __restrict__ delta, const float* __restrict__ xc,
                        const float* __restrict__ Bc, const float* __restrict__ A_log,
                        float* __restrict__ aggA, float* __restrict__ aggB){
  int b = blockIdx.x;                       // 3072 = 3*256*4
  int ng = b & 3, ch = (b>>2)&255, s = b>>10;
  int d = threadIdx.x;
  int n0 = ng*4;
  float Aa[4], P[4] = {1.f,1.f,1.f,1.f}, S[4] = {0.f,0.f,0.f,0.f};
  #pragma unroll
  for(int j=0;j<4;j++) Aa[j] = -__expf(A_log[d*NST + n0 + j]);
  int base = s*L + ch*CT;
  #pragma unroll
  for(int st=0; st<CT; st++){
    int row = base + st;
    float dl = delta[row*DI + d];
    float u  = xc[row*DI + d];
    float4 bv = *(const float4*)&Bc[row*NST + n0];
    float dlu = dl*u;
    float a;
    a = __expf(dl*Aa[0]); S[0] = a*S[0] + dlu*bv.x; P[0] *= a;
    a = __expf(dl*Aa[1]); S[1] = a*S[1] + dlu*bv.y; P[1] *= a;
    a = __expf(dl*Aa[2]); S[2] = a*S[2] + dlu*bv.z; P[2] *= a;
    a = __expf(dl*Aa[3]); S[3] = a*S[3] + dlu*bv.w; P[3] *= a;
  }
  int idx0 = ch*R3 + s*256 + d;
  #pragma unroll
  for(int j=0;j<4;j++){
    int idx = idx0 + (n0+j)*768;
    aggA[idx] = P[j]; aggB[idx] = S[j];
  }
}

// K6: prefix over 256 chunks — 8 segments of 32 per state, two-pass in-block
__global__ void k_scanB(const float* __restrict__ aggA, const float* __restrict__ aggB,
                        float* __restrict__ hIn){
  __shared__ float PA[32][9], PB[32][9];
  int tid = threadIdx.x;
  int jl = tid & 31, seg = tid >> 5;         // 32 states x 8 segments
  int j = blockIdx.x*32 + jl;                // 384 blocks
  int c0 = seg*32;
  // pass1: segment aggregate (P,S)
  float P = 1.f, S = 0.f;
  for(int i=0;i<32;i++){
    int c = c0 + i;
    float a = aggA[c*R3 + j], b = aggB[c*R3 + j];
    S = a*S + b; P = a*P;
  }
  PA[jl][seg] = P; PB[jl][seg] = S;
  __syncthreads();
  // serial compose over 8 segments (one thread per state)
  if(tid < 32){
    float h = 0.f;
    #pragma unroll
    for(int sg=0; sg<8; sg++){
      float p = PA[tid][sg], s2 = PB[tid][sg];
      PA[tid][sg] = h;                       // repurpose: segment-start state
      h = p*h + s2;
    }
  }
  __syncthreads();
  // pass2: replay prefix within segment
  float h = PA[jl][seg];
  for(int i=0;i<32;i++){
    int c = c0 + i;
    hIn[c*R3 + j] = h;
    h = aggA[c*R3 + j]*h + aggB[c*R3 + j];
  }
}

// K7: scan pass C — 16 states/thread, CT=16, gate + store yz
__global__ void k_scanC(const float* __restrict__ delta, const float* __restrict__ xc,
                        const float* __restrict__ Bc, const float* __restrict__ Cc,
                        const float* __restrict__ A_log, const float* __restrict__ Dp,
                        const float* __restrict__ Z, const float* __restrict__ hIn,
                        float* __restrict__ yz){
  int b = blockIdx.x;                 // 768 = 3*256
  int ch = b & 255, s = b >> 8;
  int d = threadIdx.x;
  float Aa[16], h[16];
  #pragma unroll
  for(int n=0;n<16;n++) Aa[n] = -__expf(A_log[d*NST + n]);
  #pragma unroll
  for(int n=0;n<16;n++) h[n] = hIn[ch*R3 + n*768 + s*256 + d];
  float Dv = Dp[d];
  int base = s*L + ch*CT;
  #pragma unroll 2
  for(int st=0; st<CT; st++){
    int row = base + st;
    float dl = delta[row*DI + d];
    float u  = xc[row*DI + d];
    float dlu = dl*u;
    const float4* Bp = (const float4*)&Bc[row*NST];
    const float4* Cp = (const float4*)&Cc[row*NST];
    float y = u*Dv;
    #pragma unroll
    for(int q=0;q<4;q++){
      float4 bv = Bp[q], cv = Cp[q];
      float a;
      a = __expf(dl*Aa[4*q+0]); h[4*q+0] = a*h[4*q+0] + dlu*bv.x; y += h[4*q+0]*cv.x;
      a = __expf(dl*Aa[4*q+1]); h[4*q+1] = a*h[4*q+1] + dlu*bv.y; y += h[4*q+1]*cv.y;
      a = __expf(dl*Aa[4*q+2]); h[4*q+2] = a*h[4*q+2] + dlu*bv.z; y += h[4*q+2]*cv.z;
      a = __expf(dl*Aa[4*q+3]); h[4*q+3] = a*h[4*q+3] + dlu*bv.w; y += h[4*q+3]*cv.w;
    }
    int l = ch*CT + st;
    int p = permf(s, l);
    float zv = Z[p*512 + 256 + d];
    yz[(s*L + l)*DI + d] = y * siluf(zv);
  }
}

// K8: out1 partials (tile 64x128, split-K=6, two 64-k phases, 51KB LDS)
__global__ void k_proj(const float* __restrict__ yz, const float* __restrict__ Mw,
                       float* __restrict__ pp){
  __shared__ float As[64][68];     // [r][k]
  __shared__ float Bs[64][132];    // [k][o]
  int p0 = blockIdx.x*64; int kc = blockIdx.y;  // 0..5
  int s = kc >> 1, d0 = (kc & 1)*128;
  int tid = threadIdx.x;
  int og = tid & 15, r4 = tid >> 4;
  float acc[4][8] = {};
  for(int kk=0; kk<2; kk++){
    int kb = d0 + kk*64;
    for(int q=0;q<4;q++){
      int f = q*1024 + tid*4; int r = f>>6, k = f&63;
      float4 a = *(const float4*)&yz[(s*L + p0 + r)*DI + kb + k];
      *(float4*)&As[r][k] = a;
    }
    for(int q=0;q<8;q++){
      int f = q*1024 + tid*4; int k = f>>7, o = f&127;
      float4 b = *(const float4*)&Mw[(s*256 + kb + k)*128 + o];
      *(float4*)&Bs[k][o] = b;
    }
    __syncthreads();
    for(int k=0;k<64;k++){
      float a[4];
      #pragma unroll
      for(int i=0;i<4;i++) a[i] = As[r4*4+i][k];
      #pragma unroll
      for(int j=0;j<8;j++){
        float bb = Bs[k][og+16*j];
        #pragma unroll
        for(int i=0;i<4;i++) acc[i][j] += a[i]*bb;
      }
    }
    __syncthreads();
  }
  float* dst = pp + kc*524288;
  #pragma unroll
  for(int i=0;i<4;i++)
    #pragma unroll
    for(int j=0;j<8;j++)
      dst[(p0+r4*4+i)*C + og + 16*j] = acc[i][j];
}

// K8b: ores = sum(pp) + x^T + pb
__global__ void k_pred(const float* __restrict__ pp, const float* __restrict__ x,
                       const float* __restrict__ pb, float* __restrict__ ores){
  __shared__ float Xs[16][129];
  int p0 = blockIdx.x*16; int tid = threadIdx.x;
  for(int q=0;q<8;q++){
    int f = q*256 + tid; int pl = f&15, o = f>>4;
    Xs[pl][o] = x[o*L + p0 + pl];
  }
  __syncthreads();
  for(int q=0;q<8;q++){
    int f = q*256 + tid; int o = f&127, pl = f>>7;
    int idx = (p0+pl)*C + o;
    float v = pp[idx] + pp[524288+idx] + pp[1048576+idx]
            + pp[1572864+idx] + pp[2097152+idx] + pp[2621440+idx];
    ores[idx] = v + Xs[pl][o] + pb[o];
  }
}

// K9b: fused LN(1e-6) + fc1 + gelu
__global__ void k_fc1(const float* __restrict__ ores, const float* __restrict__ lw,
                      const float* __restrict__ lb, const float* __restrict__ w1,
                      const float* __restrict__ b1, float* __restrict__ H){
  __shared__ float As[64][129];
  __shared__ float Bs[64][129];
  int p0 = blockIdx.x*64, j0 = blockIdx.y*64;
  int tid = threadIdx.x;
  for(int q=0;q<8;q++){
    int f = q*1024 + tid*4; int r = f>>7, k = f&127;
    float4 a = *(const float4*)&ores[(p0+r)*C + k];
    As[r][k]=a.x; As[r][k+1]=a.y; As[r][k+2]=a.z; As[r][k+3]=a.w;
    float4 b = *(const float4*)&w1[(j0+r)*C + k];
    Bs[r][k]=b.x; Bs[r][k+1]=b.y; Bs[r][k+2]=b.z; Bs[r][k+3]=b.w;
  }
  __syncthreads();
  {
    int r = tid>>2, kg = tid&3;
    float s=0.f, sq=0.f;
    #pragma unroll
    for(int i=0;i<32;i++){
      int k = kg*32 + ((i + kg*8)&31);
      float v = As[r][k]; s += v; sq += v*v;
    }
    s  += __shfl_xor(s,1);  s  += __shfl_xor(s,2);
    sq += __shfl_xor(sq,1); sq += __shfl_xor(sq,2);
    float m1 = s*(1.f/C);
    float r1 = rsqrtf(sq*(1.f/C) - m1*m1 + 1e-6f);
    #pragma unroll
    for(int i=0;i<32;i++){
      int k = kg*32 + ((i + kg*8)&31);
      As[r][k] = lw[k]*((As[r][k]-m1)*r1) + lb[k];
    }
  }
  __syncthreads();
  int og = tid & 15, r4 = tid >> 4;
  float acc[4][4] = {};
  for(int k=0;k<128;k++){
    float a[4], b[4];
    #pragma unroll
    for(int i=0;i<4;i++) a[i] = As[r4*4+i][k];
    #pragma unroll
    for(int j=0;j<4;j++) b[j] = Bs[og+16*j][k];
    #pragma unroll
    for(int i=0;i<4;i++)
      #pragma unroll
      for(int j=0;j<4;j++) acc[i][j] += a[i]*b[j];
  }
  #pragma unroll
  for(int i=0;i<4;i++)
    #pragma unroll
    for(int j=0;j<4;j++){
      int jj = j0 + og + 16*j;
      H[(p0+r4*4+i)*512 + jj] = geluf(acc[i][j] + b1[jj]);
    }
}

// K9c: fc2 partials (tile 64x128, split-K=4, two 64-k phases, 52KB LDS)
__global__ void k_fc2(const float* __restrict__ H, const float* __restrict__ w2,
                      float* __restrict__ fp){
  __shared__ float As[64][68];     // [r][k]
  __shared__ float Bs[128][68];    // [o][k]
  int p0 = blockIdx.x*64; int kc = blockIdx.y;
  int tid = threadIdx.x;
  int og = tid & 15, r4 = tid >> 4;
  float acc[4][8] = {};
  for(int kk=0; kk<2; kk++){
    int kb = kc*128 + kk*64;
    for(int q=0;q<4;q++){
      int f = q*1024 + tid*4; int r = f>>6, k = f&63;
      float4 a = *(const float4*)&H[(p0+r)*512 + kb + k];
      *(float4*)&As[r][k] = a;
    }
    for(int q=0;q<8;q++){
      int f = q*1024 + tid*4; int o = f>>6, k = f&63;
      float4 b = *(const float4*)&w2[o*512 + kb + k];
      *(float4*)&Bs[o][k] = b;
    }
    __syncthreads();
    for(int k=0;k<64;k++){
      float a[4];
      #pragma unroll
      for(int i=0;i<4;i++) a[i] = As[r4*4+i][k];
      #pragma unroll
      for(int j=0;j<8;j++){
        float bb = Bs[og+16*j][k];
        #pragma unroll
        for(int i=0;i<4;i++) acc[i][j] += a[i]*bb;
      }
    }
    __syncthreads();
  }
  float* dst = fp + kc*524288;
  #pragma unroll
  for(int i=0;i<4;i++)
    #pragma unroll
    for(int j=0;j<8;j++)
      dst[(p0+r4*4+i)*C + og + 16*j] = acc[i][j];
}

// K9d: out = sum(fp) + b2 + ores, transposed store
__global__ void k_fred(const float* __restrict__ fp, const float* __restrict__ b2,
                       const float* __restrict__ ores, float* __restrict__ out){
  __shared__ float S[128][17];
  int p0 = blockIdx.x*16; int tid = threadIdx.x;
  for(int q=0;q<8;q++){
    int f = q*256 + tid; int o = f&127, pl = f>>7;
    int idx = (p0+pl)*C + o;
    float v = fp[idx] + fp[524288+idx] + fp[1048576+idx] + fp[1572864+idx];
    S[o][pl] = v + b2[o] + ores[idx];
  }
  __syncthreads();
  for(int q=0;q<8;q++){
    int f = q*256 + tid; int pl = f&15, o = f>>4;
    out[o*L + p0 + pl] = S[o][pl];
  }
}

extern "C" void kernel_launch(void* const* d_in, const int* in_sizes, int n_in,
                              void* d_out, int out_size, void* d_ws, size_t ws_size,
                              hipStream_t stream) {
  const float* x     = (const float*)d_in[0];
  const float* ln_w  = (const float*)d_in[1];
  const float* ln_b  = (const float*)d_in[2];
  const float* mw    = (const float*)d_in[3];
  const float* mb    = (const float*)d_in[4];
  const float* ipw   = (const float*)d_in[5];
  const float* cw    = (const float*)d_in[6];
  const float* cb    = (const float*)d_in[7];
  const float* xpw   = (const float*)d_in[8];
  const float* dtw   = (const float*)d_in[9];
  const float* dtb   = (const float*)d_in[10];
  const float* A_log = (const float*)d_in[11];
  const float* Dp    = (const float*)d_in[12];
  const float* opw   = (const float*)d_in[13];
  const float* pw    = (const float*)d_in[14];
  const float* pb    = (const float*)d_in[15];
  const float* w1    = (const float*)d_in[16];
  const float* b1    = (const float*)d_in[17];
  const float* w2    = (const float*)d_in[18];
  const float* b2    = (const float*)d_in[19];
  float* out = (float*)d_out;

  float* ws = (float*)d_ws;
  float* Z     = ws;                       // 2097152
  float* xc    = Z     + 2097152;          // 3145728
  float* delta = xc    + 3145728;          // 3145728
  float* dt    = delta + 3145728;          // 98304 (spacer)
  float* Bc    = dt    + 98304;            // 196608
  float* Cc    = Bc    + 196608;           // 196608
  float* aggA  = Cc    + 196608;           // 3145728 (256 chunks * 12288)
  float* aggB  = aggA  + 3145728;          // 3145728
  float* hIn   = aggB  + 3145728;          // 3145728
  float* Mw    = hIn   + 3145728;          // 98304
  float* ores  = Mw    + 98304;            // 524288
  (void)dt;
  // aliases (dead-after-scanC regions reused)
  float* yz = aggA;    // 3145728, after scanB consumed aggA/aggB
  float* pp = delta;   // 6*524288 = 3145728, after scanC
  float* H  = Z;       // 2097152, after scanC
  float* fp = xc;      // 4*524288 = 2097152, after scanC

  k_M     <<<384, 256, 0, stream>>>(opw, pw, Mw);
  k_lngemm<<<dim3(64,8), 256, 0, stream>>>(x, ln_w, ln_b, mw, mb, ipw, Z);
  k_conv  <<<NS*L, 256, 0, stream>>>(Z, cw, cb, xc);
  k_xd2   <<<384, 256, 0, stream>>>(xc, xpw, dtw, dtb, Bc, Cc, delta);
  k_scanA <<<3072, 256, 0, stream>>>(delta, xc, Bc, A_log, aggA, aggB);
  k_scanB <<<384, 256, 0, stream>>>(aggA, aggB, hIn);
  k_scanC <<<768, 256, 0, stream>>>(delta, xc, Bc, Cc, A_log, Dp, Z, hIn, yz);
  k_proj  <<<dim3(64,6), 256, 0, stream>>>(yz, Mw, pp);
  k_pred  <<<256, 256, 0, stream>>>(pp, x, pb, ores);
  k_fc1   <<<dim3(64,8), 256, 0, stream>>>(ores, ln_w, ln_b, w1, b1, H);
  k_fc2   <<<dim3(64,4), 256, 0, stream>>>(H, w2, fp);
  k_fred  <<<256, 256, 0, stream>>>(fp, b2, ores, out);
}

// Round 7
// 292.583 us; speedup vs baseline: 1.1658x; 1.0415x over previous
//
#include <hip/hip_runtime.h>
#include <hip/hip_bf16.h>
#include <math.h>

#define L 4096
#define C 128
#define DI 256
#define NST 16
#define NS 3
#define NCH 256
#define CT 16
#define R3 12288   // (s,d,n) = 3*256*16

__device__ __forceinline__ float siluf(float x){ return x / (1.f + __expf(-x)); }
__device__ __forceinline__ float geluf(float x){ return 0.5f*x*(1.f + erff(x*0.70710678118654752f)); }

__device__ __forceinline__ int permf(int s, int l){
  if(s==0) return l;
  if(s==1) return ((l&15)<<8) | ((l>>8)<<4) | ((l>>4)&15);
  return (((l>>4)&15)<<8) | ((l&15)<<4) | (l>>8);
}

// K0: fold out_proj & proj -> M[(s*256+d)*128+o]
__global__ void k_M(const float* __restrict__ opw, const float* __restrict__ pw,
                    float* __restrict__ Mw){
  int b = blockIdx.x;              // s*128+o
  int o = b & 127, s = b >> 7;
  int d = threadIdx.x;
  float acc = 0.f;
  for(int c=0;c<C;c++) acc += opw[c*DI + d] * pw[o*384 + s*128 + c];
  Mw[(s*256+d)*128 + o] = acc;
}

// K2: fused LN(channel,1e-6)+LN(row,1e-5), then Z = Y0 @ ipw^T. A staged k-major.
__global__ void k_lngemm(const float* __restrict__ x, const float* __restrict__ lw,
                         const float* __restrict__ lb, const float* __restrict__ mw,
                         const float* __restrict__ mb, const float* __restrict__ ipw,
                         float* __restrict__ Z){
  __shared__ float As[128][68];    // [c][p]
  __shared__ float Bs[64][132];    // [j][c]
  int p0 = blockIdx.x*64, j0 = blockIdx.y*64;
  int tid = threadIdx.x;
  for(int q=0;q<8;q++){
    int f = q*1024 + tid*4; int cc = f>>6, p = f&63;
    float4 v = *(const float4*)&x[cc*L + p0 + p];
    *(float4*)&As[cc][p] = v;
  }
  for(int q=0;q<8;q++){
    int f = q*1024 + tid*4; int j = f>>7, k = f&127;
    float4 b = *(const float4*)&ipw[(j0+j)*C + k];
    *(float4*)&Bs[j][k] = b;
  }
  __syncthreads();
  {
    int p = tid>>2, kg = tid&3;
    float s=0.f, sq=0.f;
    #pragma unroll
    for(int i=0;i<32;i++){
      int k = kg*32 + ((i + kg*2)&31);
      float v = As[k][p]; s += v; sq += v*v;
    }
    s  += __shfl_xor(s,1);  s  += __shfl_xor(s,2);
    sq += __shfl_xor(sq,1); sq += __shfl_xor(sq,2);
    float m1 = s*(1.f/C);
    float r1 = rsqrtf(sq*(1.f/C) - m1*m1 + 1e-6f);
    float s2=0.f, sq2=0.f;
    #pragma unroll
    for(int i=0;i<32;i++){
      int k = kg*32 + ((i + kg*2)&31);
      float t = lw[k]*((As[k][p]-m1)*r1) + lb[k];
      s2 += t; sq2 += t*t;
    }
    s2  += __shfl_xor(s2,1);  s2  += __shfl_xor(s2,2);
    sq2 += __shfl_xor(sq2,1); sq2 += __shfl_xor(sq2,2);
    float m2 = s2*(1.f/C);
    float r2 = rsqrtf(sq2*(1.f/C) - m2*m2 + 1e-5f);
    #pragma unroll
    for(int i=0;i<32;i++){
      int k = kg*32 + ((i + kg*2)&31);
      float t = lw[k]*((As[k][p]-m1)*r1) + lb[k];
      As[k][p] = mw[k]*((t-m2)*r2) + mb[k];
    }
  }
  __syncthreads();
  int og = tid & 15, r4 = tid >> 4;
  float acc[4][4] = {};
  for(int k=0;k<128;k++){
    float4 av = *(const float4*)&As[k][r4*4];
    float a[4] = {av.x, av.y, av.z, av.w};
    float b[4];
    #pragma unroll
    for(int j=0;j<4;j++) b[j] = Bs[og+16*j][k];
    #pragma unroll
    for(int i=0;i<4;i++)
      #pragma unroll
      for(int j=0;j<4;j++) acc[i][j] += a[i]*b[j];
  }
  #pragma unroll
  for(int i=0;i<4;i++)
    #pragma unroll
    for(int j=0;j<4;j++)
      Z[(p0+r4*4+i)*512 + j0 + og + 16*j] = acc[i][j];
}

// K3: causal depthwise conv (k=4) + bias + silu
__global__ void k_conv(const float* __restrict__ Z, const float* __restrict__ cw,
                       const float* __restrict__ cb, float* __restrict__ xc){
  int bl = blockIdx.x;            // s*4096 + l
  int s = bl >> 12, l = bl & 4095;
  int d = threadIdx.x;
  float acc = cb[d];
  #pragma unroll
  for(int k=0;k<4;k++){
    int lk = l - 3 + k;
    if(lk >= 0){
      int p = permf(s, lk);
      acc += cw[d*4+k] * Z[p*512 + d];
    }
  }
  xc[bl*DI + d] = siluf(acc);
}

// K4: xdbl GEMM, scalarized weights. Block: 64 rows, 256 thr (4 waves).
// Wave w computes cols [w*10, w*10+10) for all 64 rows (lane=row).
// Ast k-major [k][row]: GEMM reads conflict-free; weight loads wave-uniform (s_load).
__global__ void k_xd3(const float* __restrict__ xc, const float* __restrict__ xpw,
                      const float* __restrict__ dtw, const float* __restrict__ dtb,
                      float* __restrict__ Bc, float* __restrict__ Cc,
                      float* __restrict__ delta){
  __shared__ float Ast[256][65];   // 66.5KB
  __shared__ float BCs[40][65];    // 10.4KB  -> ~77KB total, 2 blocks/CU
  int r0 = blockIdx.x*64;
  int tid = threadIdx.x;
  // stage 64 rows x 256 k (coalesced global, scattered b32 LDS writes)
  for(int q=0;q<16;q++){
    int f = q*1024 + tid*4; int row = f>>8, k = f&255;
    float4 v = *(const float4*)&xc[(r0+row)*DI + k];
    Ast[k+0][row]=v.x; Ast[k+1][row]=v.y; Ast[k+2][row]=v.z; Ast[k+3][row]=v.w;
  }
  __syncthreads();
  int lane = tid & 63;
  int cb0 = __builtin_amdgcn_readfirstlane((tid>>6)*10);
  const float* wp = xpw + cb0*DI;
  float acc[10] = {0.f,0.f,0.f,0.f,0.f,0.f,0.f,0.f,0.f,0.f};
  for(int k4=0;k4<64;k4++){
    int k = k4*4;
    float a0 = Ast[k+0][lane], a1 = Ast[k+1][lane];
    float a2 = Ast[k+2][lane], a3 = Ast[k+3][lane];
    #pragma unroll
    for(int j=0;j<10;j++){
      float4 w = *(const float4*)&wp[j*DI + k];   // uniform addr -> scalar load
      acc[j] += a0*w.x + a1*w.y + a2*w.z + a3*w.w;
    }
  }
  #pragma unroll
  for(int j=0;j<10;j++) BCs[cb0+j][lane] = acc[j];
  __syncthreads();
  // delta: d = tid, all 64 rows (broadcast LDS reads, coalesced global writes)
  {
    float4 ww0 = *(const float4*)&dtw[tid*8];
    float4 ww1 = *(const float4*)&dtw[tid*8+4];
    float bb = dtb[tid];
    for(int r=0;r<64;r++){
      float aa = bb + BCs[0][r]*ww0.x + BCs[1][r]*ww0.y + BCs[2][r]*ww0.z + BCs[3][r]*ww0.w
                    + BCs[4][r]*ww1.x + BCs[5][r]*ww1.y + BCs[6][r]*ww1.z + BCs[7][r]*ww1.w;
      delta[(r0+r)*DI + tid] = (aa > 20.f) ? aa : log1pf(__expf(aa));
    }
  }
  // B/C row-major writes: thread -> (r=tid>>2, ng=(tid&3)*4), float4
  {
    int r = tid>>2, ng = (tid&3)*4;
    float4 bv = make_float4(BCs[ 8+ng][r], BCs[ 9+ng][r], BCs[10+ng][r], BCs[11+ng][r]);
    float4 cv = make_float4(BCs[24+ng][r], BCs[25+ng][r], BCs[26+ng][r], BCs[27+ng][r]);
    *(float4*)&Bc[(r0+r)*NST + ng] = bv;
    *(float4*)&Cc[(r0+r)*NST + ng] = cv;
  }
}

// K5: scan pass A — chunk aggregates (P,S), CT=16, 4 states/thread
__global__ void k_scanA(const float* __restrict__ delta, const float* __restrict__ xc,
                        const float* __restrict__ Bc, const float* __restrict__ A_log,
                        float* __restrict__ aggA, float* __restrict__ aggB){
  int b = blockIdx.x;                       // 3072 = 3*256*4
  int ng = b & 3, ch = (b>>2)&255, s = b>>10;
  int d = threadIdx.x;
  int n0 = ng*4;
  float Aa[4], P[4] = {1.f,1.f,1.f,1.f}, S[4] = {0.f,0.f,0.f,0.f};
  #pragma unroll
  for(int j=0;j<4;j++) Aa[j] = -__expf(A_log[d*NST + n0 + j]);
  int base = s*L + ch*CT;
  #pragma unroll
  for(int st=0; st<CT; st++){
    int row = base + st;
    float dl = delta[row*DI + d];
    float u  = xc[row*DI + d];
    float4 bv = *(const float4*)&Bc[row*NST + n0];
    float dlu = dl*u;
    float a;
    a = __expf(dl*Aa[0]); S[0] = a*S[0] + dlu*bv.x; P[0] *= a;
    a = __expf(dl*Aa[1]); S[1] = a*S[1] + dlu*bv.y; P[1] *= a;
    a = __expf(dl*Aa[2]); S[2] = a*S[2] + dlu*bv.z; P[2] *= a;
    a = __expf(dl*Aa[3]); S[3] = a*S[3] + dlu*bv.w; P[3] *= a;
  }
  int idx0 = ch*R3 + s*256 + d;
  #pragma unroll
  for(int j=0;j<4;j++){
    int idx = idx0 + (n0+j)*768;
    aggA[idx] = P[j]; aggB[idx] = S[j];
  }
}

// K6: prefix over 256 chunks — single global pass; per-chunk prefixes in regs
__global__ void k_scanB(const float* __restrict__ aggA, const float* __restrict__ aggB,
                        float* __restrict__ hIn){
  __shared__ float PA[32][9], PB[32][9];
  int tid = threadIdx.x;
  int jl = tid & 31, seg = tid >> 5;         // 32 states x 8 segments
  int j = blockIdx.x*32 + jl;                // 384 blocks
  int c0 = seg*32;
  float pa[32], pb[32];
  float P = 1.f, S = 0.f;
  #pragma unroll
  for(int i=0;i<32;i++){
    pa[i] = P; pb[i] = S;                    // transform from segment start to chunk c0+i
    float a = aggA[(c0+i)*R3 + j], b = aggB[(c0+i)*R3 + j];
    S = a*S + b; P = a*P;
  }
  PA[jl][seg] = P; PB[jl][seg] = S;
  __syncthreads();
  if(tid < 32){
    float h = 0.f;
    #pragma unroll
    for(int sg=0; sg<8; sg++){
      float p = PA[tid][sg], s2 = PB[tid][sg];
      PA[tid][sg] = h;                       // state at segment start
      h = p*h + s2;
    }
  }
  __syncthreads();
  float h0 = PA[jl][seg];
  #pragma unroll
  for(int i=0;i<32;i++){
    hIn[(c0+i)*R3 + j] = pa[i]*h0 + pb[i];
  }
}

// K7: scan pass C — 16 states/thread, CT=16, gate + store yz
__global__ void k_scanC(const float* __restrict__ delta, const float* __restrict__ xc,
                        const float* __restrict__ Bc, const float* __restrict__ Cc,
                        const float* __restrict__ A_log, const float* __restrict__ Dp,
                        const float* __restrict__ Z, const float* __restrict__ hIn,
                        float* __restrict__ yz){
  int b = blockIdx.x;                 // 768 = 3*256
  int ch = b & 255, s = b >> 8;
  int d = threadIdx.x;
  float Aa[16], h[16];
  #pragma unroll
  for(int n=0;n<16;n++) Aa[n] = -__expf(A_log[d*NST + n]);
  #pragma unroll
  for(int n=0;n<16;n++) h[n] = hIn[ch*R3 + n*768 + s*256 + d];
  float Dv = Dp[d];
  int base = s*L + ch*CT;
  #pragma unroll 2
  for(int st=0; st<CT; st++){
    int row = base + st;
    float dl = delta[row*DI + d];
    float u  = xc[row*DI + d];
    float dlu = dl*u;
    const float4* Bp = (const float4*)&Bc[row*NST];
    const float4* Cp = (const float4*)&Cc[row*NST];
    float y = u*Dv;
    #pragma unroll
    for(int q=0;q<4;q++){
      float4 bv = Bp[q], cv = Cp[q];
      float a;
      a = __expf(dl*Aa[4*q+0]); h[4*q+0] = a*h[4*q+0] + dlu*bv.x; y += h[4*q+0]*cv.x;
      a = __expf(dl*Aa[4*q+1]); h[4*q+1] = a*h[4*q+1] + dlu*bv.y; y += h[4*q+1]*cv.y;
      a = __expf(dl*Aa[4*q+2]); h[4*q+2] = a*h[4*q+2] + dlu*bv.z; y += h[4*q+2]*cv.z;
      a = __expf(dl*Aa[4*q+3]); h[4*q+3] = a*h[4*q+3] + dlu*bv.w; y += h[4*q+3]*cv.w;
    }
    int l = ch*CT + st;
    int p = permf(s, l);
    float zv = Z[p*512 + 256 + d];
    yz[(s*L + l)*DI + d] = y * siluf(zv);
  }
}

// K8: out1 partials (tile 64x128, split-K=6, two 64-k phases, 51KB LDS)
__global__ void k_proj(const float* __restrict__ yz, const float* __restrict__ Mw,
                       float* __restrict__ pp){
  __shared__ float As[64][68];     // [r][k]
  __shared__ float Bs[64][132];    // [k][o]
  int p0 = blockIdx.x*64; int kc = blockIdx.y;  // 0..5
  int s = kc >> 1, d0 = (kc & 1)*128;
  int tid = threadIdx.x;
  int og = tid & 15, r4 = tid >> 4;
  float acc[4][8] = {};
  for(int kk=0; kk<2; kk++){
    int kb = d0 + kk*64;
    for(int q=0;q<4;q++){
      int f = q*1024 + tid*4; int r = f>>6, k = f&63;
      float4 a = *(const float4*)&yz[(s*L + p0 + r)*DI + kb + k];
      *(float4*)&As[r][k] = a;
    }
    for(int q=0;q<8;q++){
      int f = q*1024 + tid*4; int k = f>>7, o = f&127;
      float4 b = *(const float4*)&Mw[(s*256 + kb + k)*128 + o];
      *(float4*)&Bs[k][o] = b;
    }
    __syncthreads();
    for(int k=0;k<64;k++){
      float a[4];
      #pragma unroll
      for(int i=0;i<4;i++) a[i] = As[r4*4+i][k];
      #pragma unroll
      for(int j=0;j<8;j++){
        float bb = Bs[k][og+16*j];
        #pragma unroll
        for(int i=0;i<4;i++) acc[i][j] += a[i]*bb;
      }
    }
    __syncthreads();
  }
  float* dst = pp + kc*524288;
  #pragma unroll
  for(int i=0;i<4;i++)
    #pragma unroll
    for(int j=0;j<8;j++)
      dst[(p0+r4*4+i)*C + og + 16*j] = acc[i][j];
}

// K8b: ores = sum(pp) + x^T + pb
__global__ void k_pred(const float* __restrict__ pp, const float* __restrict__ x,
                       const float* __restrict__ pb, float* __restrict__ ores){
  __shared__ float Xs[16][129];
  int p0 = blockIdx.x*16; int tid = threadIdx.x;
  for(int q=0;q<8;q++){
    int f = q*256 + tid; int pl = f&15, o = f>>4;
    Xs[pl][o] = x[o*L + p0 + pl];
  }
  __syncthreads();
  for(int q=0;q<8;q++){
    int f = q*256 + tid; int o = f&127, pl = f>>7;
    int idx = (p0+pl)*C + o;
    float v = pp[idx] + pp[524288+idx] + pp[1048576+idx]
            + pp[1572864+idx] + pp[2097152+idx] + pp[2621440+idx];
    ores[idx] = v + Xs[pl][o] + pb[o];
  }
}

// K9b: fused LN(1e-6) + fc1 + gelu
__global__ void k_fc1(const float* __restrict__ ores, const float* __restrict__ lw,
                      const float* __restrict__ lb, const float* __restrict__ w1,
                      const float* __restrict__ b1, float* __restrict__ H){
  __shared__ float As[64][129];
  __shared__ float Bs[64][129];
  int p0 = blockIdx.x*64, j0 = blockIdx.y*64;
  int tid = threadIdx.x;
  for(int q=0;q<8;q++){
    int f = q*1024 + tid*4; int r = f>>7, k = f&127;
    float4 a = *(const float4*)&ores[(p0+r)*C + k];
    As[r][k]=a.x; As[r][k+1]=a.y; As[r][k+2]=a.z; As[r][k+3]=a.w;
    float4 b = *(const float4*)&w1[(j0+r)*C + k];
    Bs[r][k]=b.x; Bs[r][k+1]=b.y; Bs[r][k+2]=b.z; Bs[r][k+3]=b.w;
  }
  __syncthreads();
  {
    int r = tid>>2, kg = tid&3;
    float s=0.f, sq=0.f;
    #pragma unroll
    for(int i=0;i<32;i++){
      int k = kg*32 + ((i + kg*8)&31);
      float v = As[r][k]; s += v; sq += v*v;
    }
    s  += __shfl_xor(s,1);  s  += __shfl_xor(s,2);
    sq += __shfl_xor(sq,1); sq += __shfl_xor(sq,2);
    float m1 = s*(1.f/C);
    float r1 = rsqrtf(sq*(1.f/C) - m1*m1 + 1e-6f);
    #pragma unroll
    for(int i=0;i<32;i++){
      int k = kg*32 + ((i + kg*8)&31);
      As[r][k] = lw[k]*((As[r][k]-m1)*r1) + lb[k];
    }
  }
  __syncthreads();
  int og = tid & 15, r4 = tid >> 4;
  float acc[4][4] = {};
  for(int k=0;k<128;k++){
    float a[4], b[4];
    #pragma unroll
    for(int i=0;i<4;i++) a[i] = As[r4*4+i][k];
    #pragma unroll
    for(int j=0;j<4;j++) b[j] = Bs[og+16*j][k];
    #pragma unroll
    for(int i=0;i<4;i++)
      #pragma unroll
      for(int j=0;j<4;j++) acc[i][j] += a[i]*b[j];
  }
  #pragma unroll
  for(int i=0;i<4;i++)
    #pragma unroll
    for(int j=0;j<4;j++){
      int jj = j0 + og + 16*j;
      H[(p0+r4*4+i)*512 + jj] = geluf(acc[i][j] + b1[jj]);
    }
}

// K9c: fc2 partials (tile 64x128, split-K=4, two 64-k phases, 52KB LDS)
__global__ void k_fc2(const float* __restrict__ H, const float* __restrict__ w2,
                      float* __restrict__ fp){
  __shared__ float As[64][68];     // [r][k]
  __shared__ float Bs[128][68];    // [o][k]
  int p0 = blockIdx.x*64; int kc = blockIdx.y;
  int tid = threadIdx.x;
  int og = tid & 15, r4 = tid >> 4;
  float acc[4][8] = {};
  for(int kk=0; kk<2; kk++){
    int kb = kc*128 + kk*64;
    for(int q=0;q<4;q++){
      int f = q*1024 + tid*4; int r = f>>6, k = f&63;
      float4 a = *(const float4*)&H[(p0+r)*512 + kb + k];
      *(float4*)&As[r][k] = a;
    }
    for(int q=0;q<8;q++){
      int f = q*1024 + tid*4; int o = f>>6, k = f&63;
      float4 b = *(const float4*)&w2[o*512 + kb + k];
      *(float4*)&Bs[o][k] = b;
    }
    __syncthreads();
    for(int k=0;k<64;k++){
      float a[4];
      #pragma unroll
      for(int i=0;i<4;i++) a[i] = As[r4*4+i][k];
      #pragma unroll
      for(int j=0;j<8;j++){
        float bb = Bs[og+16*j][k];
        #pragma unroll
        for(int i=0;i<4;i++) acc[i][j] += a[i]*bb;
      }
    }
    __syncthreads();
  }
  float* dst = fp + kc*524288;
  #pragma unroll
  for(int i=0;i<4;i++)
    #pragma unroll
    for(int j=0;j<8;j++)
      dst[(p0+r4*4+i)*C + og + 16*j] = acc[i][j];
}

// K9d: out = sum(fp) + b2 + ores, transposed store
__global__ void k_fred(const float* __restrict__ fp, const float* __restrict__ b2,
                       const float* __restrict__ ores, float* __restrict__ out){
  __shared__ float S[128][17];
  int p0 = blockIdx.x*16; int tid = threadIdx.x;
  for(int q=0;q<8;q++){
    int f = q*256 + tid; int o = f&127, pl = f>>7;
    int idx = (p0+pl)*C + o;
    float v = fp[idx] + fp[524288+idx] + fp[1048576+idx] + fp[1572864+idx];
    S[o][pl] = v + b2[o] + ores[idx];
  }
  __syncthreads();
  for(int q=0;q<8;q++){
    int f = q*256 + tid; int pl = f&15, o = f>>4;
    out[o*L + p0 + pl] = S[o][pl];
  }
}

extern "C" void kernel_launch(void* const* d_in, const int* in_sizes, int n_in,
                              void* d_out, int out_size, void* d_ws, size_t ws_size,
                              hipStream_t stream) {
  const float* x     = (const float*)d_in[0];
  const float* ln_w  = (const float*)d_in[1];
  const float* ln_b  = (const float*)d_in[2];
  const float* mw    = (const float*)d_in[3];
  const float* mb    = (const float*)d_in[4];
  const float* ipw   = (const float*)d_in[5];
  const float* cw    = (const float*)d_in[6];
  const float* cb    = (const float*)d_in[7];
  const float* xpw   = (const float*)d_in[8];
  const float* dtw   = (const float*)d_in[9];
  const float* dtb   = (const float*)d_in[10];
  const float* A_log = (const float*)d_in[11];
  const float* Dp    = (const float*)d_in[12];
  const float* opw   = (const float*)d_in[13];
  const float* pw    = (const float*)d_in[14];
  const float* pb    = (const float*)d_in[15];
  const float* w1    = (const float*)d_in[16];
  const float* b1    = (const float*)d_in[17];
  const float* w2    = (const float*)d_in[18];
  const float* b2    = (const float*)d_in[19];
  float* out = (float*)d_out;

  float* ws = (float*)d_ws;
  float* Z     = ws;                       // 2097152
  float* xc    = Z     + 2097152;          // 3145728
  float* delta = xc    + 3145728;          // 3145728
  float* dt    = delta + 3145728;          // 98304 (spacer)
  float* Bc    = dt    + 98304;            // 196608
  float* Cc    = Bc    + 196608;           // 196608
  float* aggA  = Cc    + 196608;           // 3145728 (256 chunks * 12288)
  float* aggB  = aggA  + 3145728;          // 3145728
  float* hIn   = aggB  + 3145728;          // 3145728
  float* Mw    = hIn   + 3145728;          // 98304
  float* ores  = Mw    + 98304;            // 524288
  (void)dt;
  // aliases (dead-after-scanC regions reused)
  float* yz = aggA;    // 3145728, after scanB consumed aggA/aggB
  float* pp = delta;   // 6*524288 = 3145728, after scanC
  float* H  = Z;       // 2097152, after scanC
  float* fp = xc;      // 4*524288 = 2097152, after scanC

  k_M     <<<384, 256, 0, stream>>>(opw, pw, Mw);
  k_lngemm<<<dim3(64,8), 256, 0, stream>>>(x, ln_w, ln_b, mw, mb, ipw, Z);
  k_conv  <<<NS*L, 256, 0, stream>>>(Z, cw, cb, xc);
  k_xd3   <<<192, 256, 0, stream>>>(xc, xpw, dtw, dtb, Bc, Cc, delta);
  k_scanA <<<3072, 256, 0, stream>>>(delta, xc, Bc, A_log, aggA, aggB);
  k_scanB <<<384, 256, 0, stream>>>(aggA, aggB, hIn);
  k_scanC <<<768, 256, 0, stream>>>(delta, xc, Bc, Cc, A_log, Dp, Z, hIn, yz);
  k_proj  <<<dim3(64,6), 256, 0, stream>>>(yz, Mw, pp);
  k_pred  <<<256, 256, 0, stream>>>(pp, x, pb, ores);
  k_fc1   <<<dim3(64,8), 256, 0, stream>>>(ores, ln_w, ln_b, w1, b1, H);
  k_fc2   <<<dim3(64,4), 256, 0, stream>>>(H, w2, fp);
  k_fred  <<<256, 256, 0, stream>>>(fp, b2, ores, out);
}

// Round 8
// 274.285 us; speedup vs baseline: 1.2436x; 1.0667x over previous
//
#include <hip/hip_runtime.h>
#include <hip/hip_bf16.h>
#include <math.h>

#define L 4096
#define C 128
#define DI 256
#define NST 16
#define NS 3
#define NCH 256
#define CT 16
#define R3 12288   // (s,d,n) = 3*256*16

__device__ __forceinline__ float siluf(float x){ return x / (1.f + __expf(-x)); }
__device__ __forceinline__ float geluf(float x){ return 0.5f*x*(1.f + erff(x*0.70710678118654752f)); }

__device__ __forceinline__ int permf(int s, int l){
  if(s==0) return l;
  if(s==1) return ((l&15)<<8) | ((l>>8)<<4) | ((l>>4)&15);
  return (((l>>4)&15)<<8) | ((l&15)<<4) | (l>>8);
}

// K0: fold out_proj & proj -> M[(s*256+d)*128+o]
__global__ void k_M(const float* __restrict__ opw, const float* __restrict__ pw,
                    float* __restrict__ Mw){
  int b = blockIdx.x;              // s*128+o
  int o = b & 127, s = b >> 7;
  int d = threadIdx.x;
  float acc = 0.f;
  for(int c=0;c<C;c++) acc += opw[c*DI + d] * pw[o*384 + s*128 + c];
  Mw[(s*256+d)*128 + o] = acc;
}

// K2: fused LN(channel,1e-6)+LN(row,1e-5), then Z = Y0 @ ipw^T. A staged k-major.
__global__ void k_lngemm(const float* __restrict__ x, const float* __restrict__ lw,
                         const float* __restrict__ lb, const float* __restrict__ mw,
                         const float* __restrict__ mb, const float* __restrict__ ipw,
                         float* __restrict__ Z){
  __shared__ float As[128][68];    // [c][p]
  __shared__ float Bs[64][132];    // [j][c]
  int p0 = blockIdx.x*64, j0 = blockIdx.y*64;
  int tid = threadIdx.x;
  for(int q=0;q<8;q++){
    int f = q*1024 + tid*4; int cc = f>>6, p = f&63;
    float4 v = *(const float4*)&x[cc*L + p0 + p];
    *(float4*)&As[cc][p] = v;
  }
  for(int q=0;q<8;q++){
    int f = q*1024 + tid*4; int j = f>>7, k = f&127;
    float4 b = *(const float4*)&ipw[(j0+j)*C + k];
    *(float4*)&Bs[j][k] = b;
  }
  __syncthreads();
  {
    int p = tid>>2, kg = tid&3;
    float s=0.f, sq=0.f;
    #pragma unroll
    for(int i=0;i<32;i++){
      int k = kg*32 + ((i + kg*2)&31);
      float v = As[k][p]; s += v; sq += v*v;
    }
    s  += __shfl_xor(s,1);  s  += __shfl_xor(s,2);
    sq += __shfl_xor(sq,1); sq += __shfl_xor(sq,2);
    float m1 = s*(1.f/C);
    float r1 = rsqrtf(sq*(1.f/C) - m1*m1 + 1e-6f);
    float s2=0.f, sq2=0.f;
    #pragma unroll
    for(int i=0;i<32;i++){
      int k = kg*32 + ((i + kg*2)&31);
      float t = lw[k]*((As[k][p]-m1)*r1) + lb[k];
      s2 += t; sq2 += t*t;
    }
    s2  += __shfl_xor(s2,1);  s2  += __shfl_xor(s2,2);
    sq2 += __shfl_xor(sq2,1); sq2 += __shfl_xor(sq2,2);
    float m2 = s2*(1.f/C);
    float r2 = rsqrtf(sq2*(1.f/C) - m2*m2 + 1e-5f);
    #pragma unroll
    for(int i=0;i<32;i++){
      int k = kg*32 + ((i + kg*2)&31);
      float t = lw[k]*((As[k][p]-m1)*r1) + lb[k];
      As[k][p] = mw[k]*((t-m2)*r2) + mb[k];
    }
  }
  __syncthreads();
  int og = tid & 15, r4 = tid >> 4;
  float acc[4][4] = {};
  for(int k=0;k<128;k++){
    float4 av = *(const float4*)&As[k][r4*4];
    float a[4] = {av.x, av.y, av.z, av.w};
    float b[4];
    #pragma unroll
    for(int j=0;j<4;j++) b[j] = Bs[og+16*j][k];
    #pragma unroll
    for(int i=0;i<4;i++)
      #pragma unroll
      for(int j=0;j<4;j++) acc[i][j] += a[i]*b[j];
  }
  #pragma unroll
  for(int i=0;i<4;i++)
    #pragma unroll
    for(int j=0;j<4;j++)
      Z[(p0+r4*4+i)*512 + j0 + og + 16*j] = acc[i][j];
}

// K3: causal depthwise conv (k=4) + bias + silu
__global__ void k_conv(const float* __restrict__ Z, const float* __restrict__ cw,
                       const float* __restrict__ cb, float* __restrict__ xc){
  int bl = blockIdx.x;            // s*4096 + l
  int s = bl >> 12, l = bl & 4095;
  int d = threadIdx.x;
  float acc = cb[d];
  #pragma unroll
  for(int k=0;k<4;k++){
    int lk = l - 3 + k;
    if(lk >= 0){
      int p = permf(s, lk);
      acc += cw[d*4+k] * Z[p*512 + d];
    }
  }
  xc[bl*DI + d] = siluf(acc);
}

// K4a: xdbl GEMM partials, split-K=2. Grid (384, 2). 256 thr, 32 rows/block.
// As[32][132], Ws[40][132]: aligned float4 staging (granule stride 33, <=2-way).
// Thread (r=tid&31, cg=tid>>5) computes cols cg*5..cg*5+4 over 128 k.
__global__ void k_xd4a(const float* __restrict__ xc, const float* __restrict__ xpw,
                       float* __restrict__ xp){
  __shared__ float As[32][132];
  __shared__ float Ws[40][132];
  int r0 = blockIdx.x*32;
  int k0 = blockIdx.y*128;
  int tid = threadIdx.x;
  // stage A: 32 rows x 128 k = 1024 float4
  for(int q=0;q<4;q++){
    int f = q*256 + tid; int r = f>>5, kk = (f&31)*4;
    float4 v = *(const float4*)&xc[(r0+r)*DI + k0 + kk];
    *(float4*)&As[r][kk] = v;
  }
  // stage W: 40 cols x 128 k = 1280 float4
  for(int q=0;q<5;q++){
    int f = q*256 + tid; int col = f>>5, kk = (f&31)*4;
    float4 v = *(const float4*)&xpw[col*DI + k0 + kk];
    *(float4*)&Ws[col][kk] = v;
  }
  __syncthreads();
  int r = tid & 31, cg = tid >> 5;
  float acc[5] = {0.f,0.f,0.f,0.f,0.f};
  for(int k4=0;k4<32;k4++){
    float4 a = *(const float4*)&As[r][k4*4];
    #pragma unroll
    for(int j=0;j<5;j++){
      float4 w = *(const float4*)&Ws[cg*5+j][k4*4];
      acc[j] += a.x*w.x + a.y*w.y + a.z*w.z + a.w*w.w;
    }
  }
  float* dst = xp + (blockIdx.y*12288 + r0 + r)*40 + cg*5;
  #pragma unroll
  for(int j=0;j<5;j++) dst[j] = acc[j];
}

// K4b: reduce partials + delta (softplus) + Bc/Cc writes. 768 blocks, 16 rows.
__global__ void k_xd4b(const float* __restrict__ xp, const float* __restrict__ dtw,
                       const float* __restrict__ dtb, float* __restrict__ Bc,
                       float* __restrict__ Cc, float* __restrict__ delta){
  __shared__ float xdb[40][17];   // [col][row]
  int r0 = blockIdx.x*16;
  int tid = threadIdx.x;
  for(int e=tid; e<640; e+=256){
    int row = e/40, col = e%40;
    int idx = (r0+row)*40 + col;
    xdb[col][row] = xp[idx] + xp[491520 + idx];
  }
  __syncthreads();
  // delta: d = tid, 16 rows
  {
    float4 ww0 = *(const float4*)&dtw[tid*8];
    float4 ww1 = *(const float4*)&dtw[tid*8+4];
    float bb = dtb[tid];
    #pragma unroll 4
    for(int r=0;r<16;r++){
      float aa = bb + xdb[0][r]*ww0.x + xdb[1][r]*ww0.y + xdb[2][r]*ww0.z + xdb[3][r]*ww0.w
                    + xdb[4][r]*ww1.x + xdb[5][r]*ww1.y + xdb[6][r]*ww1.z + xdb[7][r]*ww1.w;
      delta[(r0+r)*DI + tid] = (aa > 20.f) ? aa : log1pf(__expf(aa));
    }
  }
  // B/C: row-major float4 writes
  if(tid < 64){
    int rr = tid>>2, ng = (tid&3)*4;
    float4 bv = make_float4(xdb[8+ng][rr], xdb[9+ng][rr], xdb[10+ng][rr], xdb[11+ng][rr]);
    *(float4*)&Bc[(r0+rr)*NST + ng] = bv;
  } else if(tid < 128){
    int t2 = tid - 64;
    int rr = t2>>2, ng = (t2&3)*4;
    float4 cv = make_float4(xdb[24+ng][rr], xdb[25+ng][rr], xdb[26+ng][rr], xdb[27+ng][rr]);
    *(float4*)&Cc[(r0+rr)*NST + ng] = cv;
  }
}

// K5: scan pass A — chunk aggregates (P,S), CT=16, 4 states/thread
__global__ void k_scanA(const float* __restrict__ delta, const float* __restrict__ xc,
                        const float* __restrict__ Bc, const float* __restrict__ A_log,
                        float* __restrict__ aggA, float* __restrict__ aggB){
  int b = blockIdx.x;                       // 3072 = 3*256*4
  int ng = b & 3, ch = (b>>2)&255, s = b>>10;
  int d = threadIdx.x;
  int n0 = ng*4;
  float Aa[4], P[4] = {1.f,1.f,1.f,1.f}, S[4] = {0.f,0.f,0.f,0.f};
  #pragma unroll
  for(int j=0;j<4;j++) Aa[j] = -__expf(A_log[d*NST + n0 + j]);
  int base = s*L + ch*CT;
  #pragma unroll
  for(int st=0; st<CT; st++){
    int row = base + st;
    float dl = delta[row*DI + d];
    float u  = xc[row*DI + d];
    float4 bv = *(const float4*)&Bc[row*NST + n0];
    float dlu = dl*u;
    float a;
    a = __expf(dl*Aa[0]); S[0] = a*S[0] + dlu*bv.x; P[0] *= a;
    a = __expf(dl*Aa[1]); S[1] = a*S[1] + dlu*bv.y; P[1] *= a;
    a = __expf(dl*Aa[2]); S[2] = a*S[2] + dlu*bv.z; P[2] *= a;
    a = __expf(dl*Aa[3]); S[3] = a*S[3] + dlu*bv.w; P[3] *= a;
  }
  int idx0 = ch*R3 + s*256 + d;
  #pragma unroll
  for(int j=0;j<4;j++){
    int idx = idx0 + (n0+j)*768;
    aggA[idx] = P[j]; aggB[idx] = S[j];
  }
}

// K6: prefix over 256 chunks — single global pass; per-chunk prefixes in regs
__global__ void k_scanB(const float* __restrict__ aggA, const float* __restrict__ aggB,
                        float* __restrict__ hIn){
  __shared__ float PA[32][9], PB[32][9];
  int tid = threadIdx.x;
  int jl = tid & 31, seg = tid >> 5;         // 32 states x 8 segments
  int j = blockIdx.x*32 + jl;                // 384 blocks
  int c0 = seg*32;
  float pa[32], pb[32];
  float P = 1.f, S = 0.f;
  #pragma unroll
  for(int i=0;i<32;i++){
    pa[i] = P; pb[i] = S;                    // transform from segment start to chunk c0+i
    float a = aggA[(c0+i)*R3 + j], b = aggB[(c0+i)*R3 + j];
    S = a*S + b; P = a*P;
  }
  PA[jl][seg] = P; PB[jl][seg] = S;
  __syncthreads();
  if(tid < 32){
    float h = 0.f;
    #pragma unroll
    for(int sg=0; sg<8; sg++){
      float p = PA[tid][sg], s2 = PB[tid][sg];
      PA[tid][sg] = h;                       // state at segment start
      h = p*h + s2;
    }
  }
  __syncthreads();
  float h0 = PA[jl][seg];
  #pragma unroll
  for(int i=0;i<32;i++){
    hIn[(c0+i)*R3 + j] = pa[i]*h0 + pb[i];
  }
}

// K7: scan pass C — 16 states/thread, CT=16, gate + store yz
__global__ void k_scanC(const float* __restrict__ delta, const float* __restrict__ xc,
                        const float* __restrict__ Bc, const float* __restrict__ Cc,
                        const float* __restrict__ A_log, const float* __restrict__ Dp,
                        const float* __restrict__ Z, const float* __restrict__ hIn,
                        float* __restrict__ yz){
  int b = blockIdx.x;                 // 768 = 3*256
  int ch = b & 255, s = b >> 8;
  int d = threadIdx.x;
  float Aa[16], h[16];
  #pragma unroll
  for(int n=0;n<16;n++) Aa[n] = -__expf(A_log[d*NST + n]);
  #pragma unroll
  for(int n=0;n<16;n++) h[n] = hIn[ch*R3 + n*768 + s*256 + d];
  float Dv = Dp[d];
  int base = s*L + ch*CT;
  #pragma unroll 2
  for(int st=0; st<CT; st++){
    int row = base + st;
    float dl = delta[row*DI + d];
    float u  = xc[row*DI + d];
    float dlu = dl*u;
    const float4* Bp = (const float4*)&Bc[row*NST];
    const float4* Cp = (const float4*)&Cc[row*NST];
    float y = u*Dv;
    #pragma unroll
    for(int q=0;q<4;q++){
      float4 bv = Bp[q], cv = Cp[q];
      float a;
      a = __expf(dl*Aa[4*q+0]); h[4*q+0] = a*h[4*q+0] + dlu*bv.x; y += h[4*q+0]*cv.x;
      a = __expf(dl*Aa[4*q+1]); h[4*q+1] = a*h[4*q+1] + dlu*bv.y; y += h[4*q+1]*cv.y;
      a = __expf(dl*Aa[4*q+2]); h[4*q+2] = a*h[4*q+2] + dlu*bv.z; y += h[4*q+2]*cv.z;
      a = __expf(dl*Aa[4*q+3]); h[4*q+3] = a*h[4*q+3] + dlu*bv.w; y += h[4*q+3]*cv.w;
    }
    int l = ch*CT + st;
    int p = permf(s, l);
    float zv = Z[p*512 + 256 + d];
    yz[(s*L + l)*DI + d] = y * siluf(zv);
  }
}

// K8: out1 partials (tile 64x128, split-K=6, two 64-k phases, 51KB LDS)
__global__ void k_proj(const float* __restrict__ yz, const float* __restrict__ Mw,
                       float* __restrict__ pp){
  __shared__ float As[64][68];     // [r][k]
  __shared__ float Bs[64][132];    // [k][o]
  int p0 = blockIdx.x*64; int kc = blockIdx.y;  // 0..5
  int s = kc >> 1, d0 = (kc & 1)*128;
  int tid = threadIdx.x;
  int og = tid & 15, r4 = tid >> 4;
  float acc[4][8] = {};
  for(int kk=0; kk<2; kk++){
    int kb = d0 + kk*64;
    for(int q=0;q<4;q++){
      int f = q*1024 + tid*4; int r = f>>6, k = f&63;
      float4 a = *(const float4*)&yz[(s*L + p0 + r)*DI + kb + k];
      *(float4*)&As[r][k] = a;
    }
    for(int q=0;q<8;q++){
      int f = q*1024 + tid*4; int k = f>>7, o = f&127;
      float4 b = *(const float4*)&Mw[(s*256 + kb + k)*128 + o];
      *(float4*)&Bs[k][o] = b;
    }
    __syncthreads();
    for(int k=0;k<64;k++){
      float a[4];
      #pragma unroll
      for(int i=0;i<4;i++) a[i] = As[r4*4+i][k];
      #pragma unroll
      for(int j=0;j<8;j++){
        float bb = Bs[k][og+16*j];
        #pragma unroll
        for(int i=0;i<4;i++) acc[i][j] += a[i]*bb;
      }
    }
    __syncthreads();
  }
  float* dst = pp + kc*524288;
  #pragma unroll
  for(int i=0;i<4;i++)
    #pragma unroll
    for(int j=0;j<8;j++)
      dst[(p0+r4*4+i)*C + og + 16*j] = acc[i][j];
}

// K8b: ores = sum(pp) + x^T + pb
__global__ void k_pred(const float* __restrict__ pp, const float* __restrict__ x,
                       const float* __restrict__ pb, float* __restrict__ ores){
  __shared__ float Xs[16][129];
  int p0 = blockIdx.x*16; int tid = threadIdx.x;
  for(int q=0;q<8;q++){
    int f = q*256 + tid; int pl = f&15, o = f>>4;
    Xs[pl][o] = x[o*L + p0 + pl];
  }
  __syncthreads();
  for(int q=0;q<8;q++){
    int f = q*256 + tid; int o = f&127, pl = f>>7;
    int idx = (p0+pl)*C + o;
    float v = pp[idx] + pp[524288+idx] + pp[1048576+idx]
            + pp[1572864+idx] + pp[2097152+idx] + pp[2621440+idx];
    ores[idx] = v + Xs[pl][o] + pb[o];
  }
}

// K9b: fused LN(1e-6) + fc1 + gelu
__global__ void k_fc1(const float* __restrict__ ores, const float* __restrict__ lw,
                      const float* __restrict__ lb, const float* __restrict__ w1,
                      const float* __restrict__ b1, float* __restrict__ H){
  __shared__ float As[64][129];
  __shared__ float Bs[64][129];
  int p0 = blockIdx.x*64, j0 = blockIdx.y*64;
  int tid = threadIdx.x;
  for(int q=0;q<8;q++){
    int f = q*1024 + tid*4; int r = f>>7, k = f&127;
    float4 a = *(const float4*)&ores[(p0+r)*C + k];
    As[r][k]=a.x; As[r][k+1]=a.y; As[r][k+2]=a.z; As[r][k+3]=a.w;
    float4 b = *(const float4*)&w1[(j0+r)*C + k];
    Bs[r][k]=b.x; Bs[r][k+1]=b.y; Bs[r][k+2]=b.z; Bs[r][k+3]=b.w;
  }
  __syncthreads();
  {
    int r = tid>>2, kg = tid&3;
    float s=0.f, sq=0.f;
    #pragma unroll
    for(int i=0;i<32;i++){
      int k = kg*32 + ((i + kg*8)&31);
      float v = As[r][k]; s += v; sq += v*v;
    }
    s  += __shfl_xor(s,1);  s  += __shfl_xor(s,2);
    sq += __shfl_xor(sq,1); sq += __shfl_xor(sq,2);
    float m1 = s*(1.f/C);
    float r1 = rsqrtf(sq*(1.f/C) - m1*m1 + 1e-6f);
    #pragma unroll
    for(int i=0;i<32;i++){
      int k = kg*32 + ((i + kg*8)&31);
      As[r][k] = lw[k]*((As[r][k]-m1)*r1) + lb[k];
    }
  }
  __syncthreads();
  int og = tid & 15, r4 = tid >> 4;
  float acc[4][4] = {};
  for(int k=0;k<128;k++){
    float a[4], b[4];
    #pragma unroll
    for(int i=0;i<4;i++) a[i] = As[r4*4+i][k];
    #pragma unroll
    for(int j=0;j<4;j++) b[j] = Bs[og+16*j][k];
    #pragma unroll
    for(int i=0;i<4;i++)
      #pragma unroll
      for(int j=0;j<4;j++) acc[i][j] += a[i]*b[j];
  }
  #pragma unroll
  for(int i=0;i<4;i++)
    #pragma unroll
    for(int j=0;j<4;j++){
      int jj = j0 + og + 16*j;
      H[(p0+r4*4+i)*512 + jj] = geluf(acc[i][j] + b1[jj]);
    }
}

// K9c: fc2 partials (tile 64x128, split-K=4, two 64-k phases, 52KB LDS)
__global__ void k_fc2(const float* __restrict__ H, const float* __restrict__ w2,
                      float* __restrict__ fp){
  __shared__ float As[64][68];     // [r][k]
  __shared__ float Bs[128][68];    // [o][k]
  int p0 = blockIdx.x*64; int kc = blockIdx.y;
  int tid = threadIdx.x;
  int og = tid & 15, r4 = tid >> 4;
  float acc[4][8] = {};
  for(int kk=0; kk<2; kk++){
    int kb = kc*128 + kk*64;
    for(int q=0;q<4;q++){
      int f = q*1024 + tid*4; int r = f>>6, k = f&63;
      float4 a = *(const float4*)&H[(p0+r)*512 + kb + k];
      *(float4*)&As[r][k] = a;
    }
    for(int q=0;q<8;q++){
      int f = q*1024 + tid*4; int o = f>>6, k = f&63;
      float4 b = *(const float4*)&w2[o*512 + kb + k];
      *(float4*)&Bs[o][k] = b;
    }
    __syncthreads();
    for(int k=0;k<64;k++){
      float a[4];
      #pragma unroll
      for(int i=0;i<4;i++) a[i] = As[r4*4+i][k];
      #pragma unroll
      for(int j=0;j<8;j++){
        float bb = Bs[og+16*j][k];
        #pragma unroll
        for(int i=0;i<4;i++) acc[i][j] += a[i]*bb;
      }
    }
    __syncthreads();
  }
  float* dst = fp + kc*524288;
  #pragma unroll
  for(int i=0;i<4;i++)
    #pragma unroll
    for(int j=0;j<8;j++)
      dst[(p0+r4*4+i)*C + og + 16*j] = acc[i][j];
}

// K9d: out = sum(fp) + b2 + ores, transposed store
__global__ void k_fred(const float* __restrict__ fp, const float* __restrict__ b2,
                       const float* __restrict__ ores, float* __restrict__ out){
  __shared__ float S[128][17];
  int p0 = blockIdx.x*16; int tid = threadIdx.x;
  for(int q=0;q<8;q++){
    int f = q*256 + tid; int o = f&127, pl = f>>7;
    int idx = (p0+pl)*C + o;
    float v = fp[idx] + fp[524288+idx] + fp[1048576+idx] + fp[1572864+idx];
    S[o][pl] = v + b2[o] + ores[idx];
  }
  __syncthreads();
  for(int q=0;q<8;q++){
    int f = q*256 + tid; int pl = f&15, o = f>>4;
    out[o*L + p0 + pl] = S[o][pl];
  }
}

extern "C" void kernel_launch(void* const* d_in, const int* in_sizes, int n_in,
                              void* d_out, int out_size, void* d_ws, size_t ws_size,
                              hipStream_t stream) {
  const float* x     = (const float*)d_in[0];
  const float* ln_w  = (const float*)d_in[1];
  const float* ln_b  = (const float*)d_in[2];
  const float* mw    = (const float*)d_in[3];
  const float* mb    = (const float*)d_in[4];
  const float* ipw   = (const float*)d_in[5];
  const float* cw    = (const float*)d_in[6];
  const float* cb    = (const float*)d_in[7];
  const float* xpw   = (const float*)d_in[8];
  const float* dtw   = (const float*)d_in[9];
  const float* dtb   = (const float*)d_in[10];
  const float* A_log = (const float*)d_in[11];
  const float* Dp    = (const float*)d_in[12];
  const float* opw   = (const float*)d_in[13];
  const float* pw    = (const float*)d_in[14];
  const float* pb    = (const float*)d_in[15];
  const float* w1    = (const float*)d_in[16];
  const float* b1    = (const float*)d_in[17];
  const float* w2    = (const float*)d_in[18];
  const float* b2    = (const float*)d_in[19];
  float* out = (float*)d_out;

  float* ws = (float*)d_ws;
  float* Z     = ws;                       // 2097152
  float* xc    = Z     + 2097152;          // 3145728
  float* delta = xc    + 3145728;          // 3145728
  float* dt    = delta + 3145728;          // 98304 (spacer)
  float* Bc    = dt    + 98304;            // 196608
  float* Cc    = Bc    + 196608;           // 196608
  float* aggA  = Cc    + 196608;           // 3145728 (256 chunks * 12288)
  float* aggB  = aggA  + 3145728;          // 3145728
  float* hIn   = aggB  + 3145728;          // 3145728
  float* Mw    = hIn   + 3145728;          // 98304
  float* ores  = Mw    + 98304;            // 524288
  (void)dt;
  // aliases (regions reused when dead)
  float* xp = hIn;     // 983040 (2*12288*40) xdbl partials; dead once xd4b done (scanB rewrites hIn later)
  float* yz = aggA;    // 3145728, after scanB consumed aggA/aggB
  float* pp = delta;   // 6*524288 = 3145728, after scanC
  float* H  = Z;       // 2097152, after scanC
  float* fp = xc;      // 4*524288 = 2097152, after scanC

  k_M     <<<384, 256, 0, stream>>>(opw, pw, Mw);
  k_lngemm<<<dim3(64,8), 256, 0, stream>>>(x, ln_w, ln_b, mw, mb, ipw, Z);
  k_conv  <<<NS*L, 256, 0, stream>>>(Z, cw, cb, xc);
  k_xd4a  <<<dim3(384,2), 256, 0, stream>>>(xc, xpw, xp);
  k_xd4b  <<<768, 256, 0, stream>>>(xp, dtw, dtb, Bc, Cc, delta);
  k_scanA <<<3072, 256, 0, stream>>>(delta, xc, Bc, A_log, aggA, aggB);
  k_scanB <<<384, 256, 0, stream>>>(aggA, aggB, hIn);
  k_scanC <<<768, 256, 0, stream>>>(delta, xc, Bc, Cc, A_log, Dp, Z, hIn, yz);
  k_proj  <<<dim3(64,6), 256, 0, stream>>>(yz, Mw, pp);
  k_pred  <<<256, 256, 0, stream>>>(pp, x, pb, ores);
  k_fc1   <<<dim3(64,8), 256, 0, stream>>>(ores, ln_w, ln_b, w1, b1, H);
  k_fc2   <<<dim3(64,4), 256, 0, stream>>>(H, w2, fp);
  k_fred  <<<256, 256, 0, stream>>>(fp, b2, ores, out);
}

// Round 9
// 255.586 us; speedup vs baseline: 1.3346x; 1.0732x over previous
//
#include <hip/hip_runtime.h>
#include <hip/hip_bf16.h>
#include <math.h>

#define L 4096
#define C 128
#define DI 256
#define NST 16
#define NS 3
#define NCH 256
#define CT 16
#define R3 12288   // (s,d,n) = 3*256*16

typedef unsigned short u16;

__device__ __forceinline__ float siluf(float x){ return x / (1.f + __expf(-x)); }
__device__ __forceinline__ float geluf(float x){ return 0.5f*x*(1.f + erff(x*0.70710678118654752f)); }

__device__ __forceinline__ float b2f(u16 h){ return __uint_as_float(((unsigned)h)<<16); }
__device__ __forceinline__ u16 f2b(float f){
  unsigned u = __float_as_uint(f);
  return (u16)((u + 0x7FFFu + ((u>>16)&1u)) >> 16);   // RNE
}
__device__ __forceinline__ float4 b4f(const u16* p){   // 8B-aligned 4x bf16 -> float4
  ushort4 v = *(const ushort4*)p;
  return make_float4(b2f(v.x), b2f(v.y), b2f(v.z), b2f(v.w));
}

__device__ __forceinline__ int permf(int s, int l){
  if(s==0) return l;
  if(s==1) return ((l&15)<<8) | ((l>>8)<<4) | ((l>>4)&15);
  return (((l>>4)&15)<<8) | ((l&15)<<4) | (l>>8);
}

// K0: fold out_proj & proj -> M[(s*256+d)*128+o]  (fp32)
__global__ void k_M(const float* __restrict__ opw, const float* __restrict__ pw,
                    float* __restrict__ Mw){
  int b = blockIdx.x;              // s*128+o
  int o = b & 127, s = b >> 7;
  int d = threadIdx.x;
  float acc = 0.f;
  for(int c=0;c<C;c++) acc += opw[c*DI + d] * pw[o*384 + s*128 + c];
  Mw[(s*256+d)*128 + o] = acc;
}

// K2: fused LN+LN then Z = Y0 @ ipw^T. Z output bf16.
__global__ void k_lngemm(const float* __restrict__ x, const float* __restrict__ lw,
                         const float* __restrict__ lb, const float* __restrict__ mw,
                         const float* __restrict__ mb, const float* __restrict__ ipw,
                         u16* __restrict__ Zb){
  __shared__ float As[128][68];    // [c][p]
  __shared__ float Bs[64][132];    // [j][c]
  int p0 = blockIdx.x*64, j0 = blockIdx.y*64;
  int tid = threadIdx.x;
  for(int q=0;q<8;q++){
    int f = q*1024 + tid*4; int cc = f>>6, p = f&63;
    float4 v = *(const float4*)&x[cc*L + p0 + p];
    *(float4*)&As[cc][p] = v;
  }
  for(int q=0;q<8;q++){
    int f = q*1024 + tid*4; int j = f>>7, k = f&127;
    float4 b = *(const float4*)&ipw[(j0+j)*C + k];
    *(float4*)&Bs[j][k] = b;
  }
  __syncthreads();
  {
    int p = tid>>2, kg = tid&3;
    float s=0.f, sq=0.f;
    #pragma unroll
    for(int i=0;i<32;i++){
      int k = kg*32 + ((i + kg*2)&31);
      float v = As[k][p]; s += v; sq += v*v;
    }
    s  += __shfl_xor(s,1);  s  += __shfl_xor(s,2);
    sq += __shfl_xor(sq,1); sq += __shfl_xor(sq,2);
    float m1 = s*(1.f/C);
    float r1 = rsqrtf(sq*(1.f/C) - m1*m1 + 1e-6f);
    float s2=0.f, sq2=0.f;
    #pragma unroll
    for(int i=0;i<32;i++){
      int k = kg*32 + ((i + kg*2)&31);
      float t = lw[k]*((As[k][p]-m1)*r1) + lb[k];
      s2 += t; sq2 += t*t;
    }
    s2  += __shfl_xor(s2,1);  s2  += __shfl_xor(s2,2);
    sq2 += __shfl_xor(sq2,1); sq2 += __shfl_xor(sq2,2);
    float m2 = s2*(1.f/C);
    float r2 = rsqrtf(sq2*(1.f/C) - m2*m2 + 1e-5f);
    #pragma unroll
    for(int i=0;i<32;i++){
      int k = kg*32 + ((i + kg*2)&31);
      float t = lw[k]*((As[k][p]-m1)*r1) + lb[k];
      As[k][p] = mw[k]*((t-m2)*r2) + mb[k];
    }
  }
  __syncthreads();
  int og = tid & 15, r4 = tid >> 4;
  float acc[4][4] = {};
  for(int k=0;k<128;k++){
    float4 av = *(const float4*)&As[k][r4*4];
    float a[4] = {av.x, av.y, av.z, av.w};
    float b[4];
    #pragma unroll
    for(int j=0;j<4;j++) b[j] = Bs[og+16*j][k];
    #pragma unroll
    for(int i=0;i<4;i++)
      #pragma unroll
      for(int j=0;j<4;j++) acc[i][j] += a[i]*b[j];
  }
  #pragma unroll
  for(int i=0;i<4;i++)
    #pragma unroll
    for(int j=0;j<4;j++)
      Zb[(p0+r4*4+i)*512 + j0 + og + 16*j] = f2b(acc[i][j]);
}

// K3: causal depthwise conv (k=4) + bias + silu.  Z,xc bf16.
__global__ void k_conv(const u16* __restrict__ Zb, const float* __restrict__ cw,
                       const float* __restrict__ cb, u16* __restrict__ xcb){
  int bl = blockIdx.x;            // s*4096 + l
  int s = bl >> 12, l = bl & 4095;
  int d = threadIdx.x;
  float acc = cb[d];
  #pragma unroll
  for(int k=0;k<4;k++){
    int lk = l - 3 + k;
    if(lk >= 0){
      int p = permf(s, lk);
      acc += cw[d*4+k] * b2f(Zb[p*512 + d]);
    }
  }
  xcb[bl*DI + d] = f2b(siluf(acc));
}

// K4a: xdbl GEMM partials, split-K=2. xc bf16 in, xp fp32 out.
__global__ void k_xd4a(const u16* __restrict__ xcb, const float* __restrict__ xpw,
                       float* __restrict__ xp){
  __shared__ float As[32][132];
  __shared__ float Ws[40][132];
  int r0 = blockIdx.x*32;
  int k0 = blockIdx.y*128;
  int tid = threadIdx.x;
  // stage A: 32 rows x 128 k bf16 = 1024 ushort4
  for(int q=0;q<4;q++){
    int f = q*256 + tid; int r = f>>5, kk = (f&31)*4;
    float4 v = b4f(&xcb[(r0+r)*DI + k0 + kk]);
    *(float4*)&As[r][kk] = v;
  }
  // stage W: 40 cols x 128 k fp32 = 1280 float4
  for(int q=0;q<5;q++){
    int f = q*256 + tid; int col = f>>5, kk = (f&31)*4;
    float4 v = *(const float4*)&xpw[col*DI + k0 + kk];
    *(float4*)&Ws[col][kk] = v;
  }
  __syncthreads();
  int r = tid & 31, cg = tid >> 5;
  float acc[5] = {0.f,0.f,0.f,0.f,0.f};
  for(int k4=0;k4<32;k4++){
    float4 a = *(const float4*)&As[r][k4*4];
    #pragma unroll
    for(int j=0;j<5;j++){
      float4 w = *(const float4*)&Ws[cg*5+j][k4*4];
      acc[j] += a.x*w.x + a.y*w.y + a.z*w.z + a.w*w.w;
    }
  }
  float* dst = xp + (blockIdx.y*12288 + r0 + r)*40 + cg*5;
  #pragma unroll
  for(int j=0;j<5;j++) dst[j] = acc[j];
}

// K4b: reduce partials + delta (softplus, bf16 out) + Bc/Cc (fp32).
__global__ void k_xd4b(const float* __restrict__ xp, const float* __restrict__ dtw,
                       const float* __restrict__ dtb, float* __restrict__ Bc,
                       float* __restrict__ Cc, u16* __restrict__ deltab){
  __shared__ float xdb[40][17];   // [col][row]
  int r0 = blockIdx.x*16;
  int tid = threadIdx.x;
  for(int e=tid; e<640; e+=256){
    int row = e/40, col = e%40;
    int idx = (r0+row)*40 + col;
    xdb[col][row] = xp[idx] + xp[491520 + idx];
  }
  __syncthreads();
  {
    float4 ww0 = *(const float4*)&dtw[tid*8];
    float4 ww1 = *(const float4*)&dtw[tid*8+4];
    float bb = dtb[tid];
    #pragma unroll 4
    for(int r=0;r<16;r++){
      float aa = bb + xdb[0][r]*ww0.x + xdb[1][r]*ww0.y + xdb[2][r]*ww0.z + xdb[3][r]*ww0.w
                    + xdb[4][r]*ww1.x + xdb[5][r]*ww1.y + xdb[6][r]*ww1.z + xdb[7][r]*ww1.w;
      float dl = (aa > 20.f) ? aa : log1pf(__expf(aa));
      deltab[(r0+r)*DI + tid] = f2b(dl);
    }
  }
  if(tid < 64){
    int rr = tid>>2, ng = (tid&3)*4;
    float4 bv = make_float4(xdb[8+ng][rr], xdb[9+ng][rr], xdb[10+ng][rr], xdb[11+ng][rr]);
    *(float4*)&Bc[(r0+rr)*NST + ng] = bv;
  } else if(tid < 128){
    int t2 = tid - 64;
    int rr = t2>>2, ng = (t2&3)*4;
    float4 cv = make_float4(xdb[24+ng][rr], xdb[25+ng][rr], xdb[26+ng][rr], xdb[27+ng][rr]);
    *(float4*)&Cc[(r0+rr)*NST + ng] = cv;
  }
}

// K5: scan pass A — chunk aggregates (P,S) bf16 out; delta/xc bf16 in.
__global__ void k_scanA(const u16* __restrict__ deltab, const u16* __restrict__ xcb,
                        const float* __restrict__ Bc, const float* __restrict__ A_log,
                        u16* __restrict__ aggAb, u16* __restrict__ aggBb){
  int b = blockIdx.x;                       // 3072 = 3*256*4
  int ng = b & 3, ch = (b>>2)&255, s = b>>10;
  int d = threadIdx.x;
  int n0 = ng*4;
  float Aa[4], P[4] = {1.f,1.f,1.f,1.f}, S[4] = {0.f,0.f,0.f,0.f};
  #pragma unroll
  for(int j=0;j<4;j++) Aa[j] = -__expf(A_log[d*NST + n0 + j]);
  int base = s*L + ch*CT;
  #pragma unroll
  for(int st=0; st<CT; st++){
    int row = base + st;
    float dl = b2f(deltab[row*DI + d]);
    float u  = b2f(xcb[row*DI + d]);
    float4 bv = *(const float4*)&Bc[row*NST + n0];
    float dlu = dl*u;
    float a;
    a = __expf(dl*Aa[0]); S[0] = a*S[0] + dlu*bv.x; P[0] *= a;
    a = __expf(dl*Aa[1]); S[1] = a*S[1] + dlu*bv.y; P[1] *= a;
    a = __expf(dl*Aa[2]); S[2] = a*S[2] + dlu*bv.z; P[2] *= a;
    a = __expf(dl*Aa[3]); S[3] = a*S[3] + dlu*bv.w; P[3] *= a;
  }
  int idx0 = ch*R3 + s*256 + d;
  #pragma unroll
  for(int j=0;j<4;j++){
    int idx = idx0 + (n0+j)*768;
    aggAb[idx] = f2b(P[j]); aggBb[idx] = f2b(S[j]);
  }
}

// K6: prefix over 256 chunks — single pass; agg/hIn bf16.
__global__ void k_scanB(const u16* __restrict__ aggAb, const u16* __restrict__ aggBb,
                        u16* __restrict__ hInb){
  __shared__ float PA[32][9], PB[32][9];
  int tid = threadIdx.x;
  int jl = tid & 31, seg = tid >> 5;         // 32 states x 8 segments
  int j = blockIdx.x*32 + jl;                // 384 blocks
  int c0 = seg*32;
  float pa[32], pb[32];
  float P = 1.f, S = 0.f;
  #pragma unroll
  for(int i=0;i<32;i++){
    pa[i] = P; pb[i] = S;
    float a = b2f(aggAb[(c0+i)*R3 + j]), b = b2f(aggBb[(c0+i)*R3 + j]);
    S = a*S + b; P = a*P;
  }
  PA[jl][seg] = P; PB[jl][seg] = S;
  __syncthreads();
  if(tid < 32){
    float h = 0.f;
    #pragma unroll
    for(int sg=0; sg<8; sg++){
      float p = PA[tid][sg], s2 = PB[tid][sg];
      PA[tid][sg] = h;
      h = p*h + s2;
    }
  }
  __syncthreads();
  float h0 = PA[jl][seg];
  #pragma unroll
  for(int i=0;i<32;i++){
    hInb[(c0+i)*R3 + j] = f2b(pa[i]*h0 + pb[i]);
  }
}

// K7: scan pass C — bf16 streams in, yz bf16 out.
__global__ void k_scanC(const u16* __restrict__ deltab, const u16* __restrict__ xcb,
                        const float* __restrict__ Bc, const float* __restrict__ Cc,
                        const float* __restrict__ A_log, const float* __restrict__ Dp,
                        const u16* __restrict__ Zb, const u16* __restrict__ hInb,
                        u16* __restrict__ yzb){
  int b = blockIdx.x;                 // 768 = 3*256
  int ch = b & 255, s = b >> 8;
  int d = threadIdx.x;
  float Aa[16], h[16];
  #pragma unroll
  for(int n=0;n<16;n++) Aa[n] = -__expf(A_log[d*NST + n]);
  #pragma unroll
  for(int n=0;n<16;n++) h[n] = b2f(hInb[ch*R3 + n*768 + s*256 + d]);
  float Dv = Dp[d];
  int base = s*L + ch*CT;
  #pragma unroll 2
  for(int st=0; st<CT; st++){
    int row = base + st;
    float dl = b2f(deltab[row*DI + d]);
    float u  = b2f(xcb[row*DI + d]);
    float dlu = dl*u;
    const float4* Bp = (const float4*)&Bc[row*NST];
    const float4* Cp = (const float4*)&Cc[row*NST];
    float y = u*Dv;
    #pragma unroll
    for(int q=0;q<4;q++){
      float4 bv = Bp[q], cv = Cp[q];
      float a;
      a = __expf(dl*Aa[4*q+0]); h[4*q+0] = a*h[4*q+0] + dlu*bv.x; y += h[4*q+0]*cv.x;
      a = __expf(dl*Aa[4*q+1]); h[4*q+1] = a*h[4*q+1] + dlu*bv.y; y += h[4*q+1]*cv.y;
      a = __expf(dl*Aa[4*q+2]); h[4*q+2] = a*h[4*q+2] + dlu*bv.z; y += h[4*q+2]*cv.z;
      a = __expf(dl*Aa[4*q+3]); h[4*q+3] = a*h[4*q+3] + dlu*bv.w; y += h[4*q+3]*cv.w;
    }
    int l = ch*CT + st;
    int p = permf(s, l);
    float zv = b2f(Zb[p*512 + 256 + d]);
    yzb[(s*L + l)*DI + d] = f2b(y * siluf(zv));
  }
}

// K8: out1 partials (64x128 tile, split-K=6, two 64-k phases). yz bf16, pp bf16.
__global__ void k_proj(const u16* __restrict__ yzb, const float* __restrict__ Mw,
                       u16* __restrict__ ppb){
  __shared__ float As[64][68];     // [r][k]
  __shared__ float Bs[64][132];    // [k][o]
  int p0 = blockIdx.x*64; int kc = blockIdx.y;  // 0..5
  int s = kc >> 1, d0 = (kc & 1)*128;
  int tid = threadIdx.x;
  int og = tid & 15, r4 = tid >> 4;
  float acc[4][8] = {};
  for(int kk=0; kk<2; kk++){
    int kb = d0 + kk*64;
    for(int q=0;q<4;q++){
      int f = q*256 + tid; int r = f>>4, k = (f&15)*4;   // 64x64 bf16 = 1024 ushort4
      float4 a = b4f(&yzb[(s*L + p0 + r)*DI + kb + k]);
      *(float4*)&As[r][k] = a;
    }
    for(int q=0;q<8;q++){
      int f = q*1024 + tid*4; int k = f>>7, o = f&127;
      float4 b = *(const float4*)&Mw[(s*256 + kb + k)*128 + o];
      *(float4*)&Bs[k][o] = b;
    }
    __syncthreads();
    for(int k=0;k<64;k++){
      float a[4];
      #pragma unroll
      for(int i=0;i<4;i++) a[i] = As[r4*4+i][k];
      #pragma unroll
      for(int j=0;j<8;j++){
        float bb = Bs[k][og+16*j];
        #pragma unroll
        for(int i=0;i<4;i++) acc[i][j] += a[i]*bb;
      }
    }
    __syncthreads();
  }
  u16* dst = ppb + kc*524288;
  #pragma unroll
  for(int i=0;i<4;i++)
    #pragma unroll
    for(int j=0;j<8;j++)
      dst[(p0+r4*4+i)*C + og + 16*j] = f2b(acc[i][j]);
}

// K8b: ores = sum(pp) + x^T + pb   (pp bf16, ores fp32)
__global__ void k_pred(const u16* __restrict__ ppb, const float* __restrict__ x,
                       const float* __restrict__ pb, float* __restrict__ ores){
  __shared__ float Xs[16][129];
  int p0 = blockIdx.x*16; int tid = threadIdx.x;
  for(int q=0;q<8;q++){
    int f = q*256 + tid; int pl = f&15, o = f>>4;
    Xs[pl][o] = x[o*L + p0 + pl];
  }
  __syncthreads();
  for(int q=0;q<8;q++){
    int f = q*256 + tid; int o = f&127, pl = f>>7;
    int idx = (p0+pl)*C + o;
    float v = b2f(ppb[idx]) + b2f(ppb[524288+idx]) + b2f(ppb[1048576+idx])
            + b2f(ppb[1572864+idx]) + b2f(ppb[2097152+idx]) + b2f(ppb[2621440+idx]);
    ores[idx] = v + Xs[pl][o] + pb[o];
  }
}

// K9b: fused LN(1e-6) + fc1 + gelu.  H bf16 out.
__global__ void k_fc1(const float* __restrict__ ores, const float* __restrict__ lw,
                      const float* __restrict__ lb, const float* __restrict__ w1,
                      const float* __restrict__ b1, u16* __restrict__ Hb){
  __shared__ float As[64][129];
  __shared__ float Bs[64][129];
  int p0 = blockIdx.x*64, j0 = blockIdx.y*64;
  int tid = threadIdx.x;
  for(int q=0;q<8;q++){
    int f = q*1024 + tid*4; int r = f>>7, k = f&127;
    float4 a = *(const float4*)&ores[(p0+r)*C + k];
    As[r][k]=a.x; As[r][k+1]=a.y; As[r][k+2]=a.z; As[r][k+3]=a.w;
    float4 b = *(const float4*)&w1[(j0+r)*C + k];
    Bs[r][k]=b.x; Bs[r][k+1]=b.y; Bs[r][k+2]=b.z; Bs[r][k+3]=b.w;
  }
  __syncthreads();
  {
    int r = tid>>2, kg = tid&3;
    float s=0.f, sq=0.f;
    #pragma unroll
    for(int i=0;i<32;i++){
      int k = kg*32 + ((i + kg*8)&31);
      float v = As[r][k]; s += v; sq += v*v;
    }
    s  += __shfl_xor(s,1);  s  += __shfl_xor(s,2);
    sq += __shfl_xor(sq,1); sq += __shfl_xor(sq,2);
    float m1 = s*(1.f/C);
    float r1 = rsqrtf(sq*(1.f/C) - m1*m1 + 1e-6f);
    #pragma unroll
    for(int i=0;i<32;i++){
      int k = kg*32 + ((i + kg*8)&31);
      As[r][k] = lw[k]*((As[r][k]-m1)*r1) + lb[k];
    }
  }
  __syncthreads();
  int og = tid & 15, r4 = tid >> 4;
  float acc[4][4] = {};
  for(int k=0;k<128;k++){
    float a[4], b[4];
    #pragma unroll
    for(int i=0;i<4;i++) a[i] = As[r4*4+i][k];
    #pragma unroll
    for(int j=0;j<4;j++) b[j] = Bs[og+16*j][k];
    #pragma unroll
    for(int i=0;i<4;i++)
      #pragma unroll
      for(int j=0;j<4;j++) acc[i][j] += a[i]*b[j];
  }
  #pragma unroll
  for(int i=0;i<4;i++)
    #pragma unroll
    for(int j=0;j<4;j++){
      int jj = j0 + og + 16*j;
      Hb[(p0+r4*4+i)*512 + jj] = f2b(geluf(acc[i][j] + b1[jj]));
    }
}

// K9c: fc2 partials (split-K=4, two 64-k phases). H bf16 in, fp bf16 out.
__global__ void k_fc2(const u16* __restrict__ Hb, const float* __restrict__ w2,
                      u16* __restrict__ fpb){
  __shared__ float As[64][68];     // [r][k]
  __shared__ float Bs[128][68];    // [o][k]
  int p0 = blockIdx.x*64; int kc = blockIdx.y;
  int tid = threadIdx.x;
  int og = tid & 15, r4 = tid >> 4;
  float acc[4][8] = {};
  for(int kk=0; kk<2; kk++){
    int kb = kc*128 + kk*64;
    for(int q=0;q<4;q++){
      int f = q*256 + tid; int r = f>>4, k = (f&15)*4;   // 64x64 bf16
      float4 a = b4f(&Hb[(p0+r)*512 + kb + k]);
      *(float4*)&As[r][k] = a;
    }
    for(int q=0;q<8;q++){
      int f = q*1024 + tid*4; int o = f>>6, k = f&63;
      float4 b = *(const float4*)&w2[o*512 + kb + k];
      *(float4*)&Bs[o][k] = b;
    }
    __syncthreads();
    for(int k=0;k<64;k++){
      float a[4];
      #pragma unroll
      for(int i=0;i<4;i++) a[i] = As[r4*4+i][k];
      #pragma unroll
      for(int j=0;j<8;j++){
        float bb = Bs[og+16*j][k];
        #pragma unroll
        for(int i=0;i<4;i++) acc[i][j] += a[i]*bb;
      }
    }
    __syncthreads();
  }
  u16* dst = fpb + kc*524288;
  #pragma unroll
  for(int i=0;i<4;i++)
    #pragma unroll
    for(int j=0;j<8;j++)
      dst[(p0+r4*4+i)*C + og + 16*j] = f2b(acc[i][j]);
}

// K9d: out = sum(fp) + b2 + ores, transposed store (out fp32)
__global__ void k_fred(const u16* __restrict__ fpb, const float* __restrict__ b2,
                       const float* __restrict__ ores, float* __restrict__ out){
  __shared__ float S[128][17];
  int p0 = blockIdx.x*16; int tid = threadIdx.x;
  for(int q=0;q<8;q++){
    int f = q*256 + tid; int o = f&127, pl = f>>7;
    int idx = (p0+pl)*C + o;
    float v = b2f(fpb[idx]) + b2f(fpb[524288+idx]) + b2f(fpb[1048576+idx]) + b2f(fpb[1572864+idx]);
    S[o][pl] = v + b2[o] + ores[idx];
  }
  __syncthreads();
  for(int q=0;q<8;q++){
    int f = q*256 + tid; int pl = f&15, o = f>>4;
    out[o*L + p0 + pl] = S[o][pl];
  }
}

extern "C" void kernel_launch(void* const* d_in, const int* in_sizes, int n_in,
                              void* d_out, int out_size, void* d_ws, size_t ws_size,
                              hipStream_t stream) {
  const float* x     = (const float*)d_in[0];
  const float* ln_w  = (const float*)d_in[1];
  const float* ln_b  = (const float*)d_in[2];
  const float* mw    = (const float*)d_in[3];
  const float* mb    = (const float*)d_in[4];
  const float* ipw   = (const float*)d_in[5];
  const float* cw    = (const float*)d_in[6];
  const float* cb    = (const float*)d_in[7];
  const float* xpw   = (const float*)d_in[8];
  const float* dtw   = (const float*)d_in[9];
  const float* dtb   = (const float*)d_in[10];
  const float* A_log = (const float*)d_in[11];
  const float* Dp    = (const float*)d_in[12];
  const float* opw   = (const float*)d_in[13];
  const float* pw    = (const float*)d_in[14];
  const float* pb    = (const float*)d_in[15];
  const float* w1    = (const float*)d_in[16];
  const float* b1    = (const float*)d_in[17];
  const float* w2    = (const float*)d_in[18];
  const float* b2    = (const float*)d_in[19];
  float* out = (float*)d_out;

  char* wsb = (char*)d_ws;
  // bf16 streams
  u16* Zb     = (u16*)(wsb);                     //  4,194,304 B (4096*512*2)
  u16* xcb    = (u16*)(wsb +  4194304);          //  6,291,456 B (12288*256*2)
  u16* deltab = (u16*)(wsb + 10485760);          //  6,291,456 B
  u16* aggAb  = (u16*)(wsb + 16777216);          //  6,291,456 B (256*12288*2)
  u16* aggBb  = (u16*)(wsb + 23068672);          //  6,291,456 B
  u16* hInb   = (u16*)(wsb + 29360128);          //  6,291,456 B
  // fp32 tensors
  float* Bc   = (float*)(wsb + 35651584);        //    786,432 B
  float* Cc   = (float*)(wsb + 36438016);        //    786,432 B
  float* Mw   = (float*)(wsb + 37224448);        //    393,216 B
  float* ores = (float*)(wsb + 37617664);        //  2,097,152 B
  float* xp   = (float*)(wsb + 39714816);        //  3,932,160 B (2*12288*40*4)
  // aliases (regions dead when reused)
  u16* yzb = aggAb;    // 6.3MB; aggA dead after scanB
  u16* ppb = deltab;   // 6.3MB; delta dead after scanC
  u16* Hb  = Zb;       // 4MB;   Z dead after scanC
  u16* fpb = xcb;      // 4MB of 6.3MB; xc dead after scanC

  k_M     <<<384, 256, 0, stream>>>(opw, pw, Mw);
  k_lngemm<<<dim3(64,8), 256, 0, stream>>>(x, ln_w, ln_b, mw, mb, ipw, Zb);
  k_conv  <<<NS*L, 256, 0, stream>>>(Zb, cw, cb, xcb);
  k_xd4a  <<<dim3(384,2), 256, 0, stream>>>(xcb, xpw, xp);
  k_xd4b  <<<768, 256, 0, stream>>>(xp, dtw, dtb, Bc, Cc, deltab);
  k_scanA <<<3072, 256, 0, stream>>>(deltab, xcb, Bc, A_log, aggAb, aggBb);
  k_scanB <<<384, 256, 0, stream>>>(aggAb, aggBb, hInb);
  k_scanC <<<768, 256, 0, stream>>>(deltab, xcb, Bc, Cc, A_log, Dp, Zb, hInb, yzb);
  k_proj  <<<dim3(64,6), 256, 0, stream>>>(yzb, Mw, ppb);
  k_pred  <<<256, 256, 0, stream>>>(ppb, x, pb, ores);
  k_fc1   <<<dim3(64,8), 256, 0, stream>>>(ores, ln_w, ln_b, w1, b1, Hb);
  k_fc2   <<<dim3(64,4), 256, 0, stream>>>(Hb, w2, fpb);
  k_fred  <<<256, 256, 0, stream>>>(fpb, b2, ores, out);
}